// Round 15
// baseline (277.470 us; speedup 1.0000x reference)
//
#include <hip/hip_runtime.h>
#include <math.h>

#define NN 8192
#define KK 32
#define DD 256
#define PP 64
#define HH 8
#define DHH 32
#define NBATCH 32
#define NCHAIN 64

typedef __attribute__((ext_vector_type(8))) short bf16x8;
typedef __attribute__((ext_vector_type(4))) float f32x4;

// ---------------- helpers ----------------
__device__ __forceinline__ float gelu_f(float x) {
    float x3 = x * x * x;
    float e = __expf(fmaf(x3, -0.07135481f, x * -1.59576912f));
    return __fdividef(x, 1.f + e);
}

__device__ __forceinline__ float wave_sum64(float v) {
    #pragma unroll
    for (int m = 32; m > 0; m >>= 1) v += __shfl_xor(v, m);
    return v;
}

__device__ __forceinline__ ushort f2bf(float x) {
    union { float f; unsigned int u; } v; v.f = x;
    unsigned int r = v.u + 0x7fffu + ((v.u >> 16) & 1u);
    return (ushort)(r >> 16);
}

__device__ __forceinline__ float bf2f(ushort u) {
    union { unsigned int u; float f; } v; v.u = ((unsigned int)u) << 16;
    return v.f;
}

__device__ __forceinline__ uint pk2(float a, float b) {
    return (uint)f2bf(a) | ((uint)f2bf(b) << 16);
}

__device__ __forceinline__ void frames_of(const float* __restrict__ p, float R[9]) {
    float nx = p[0], ny = p[1], nz = p[2];
    float cax = p[3], cay = p[4], caz = p[5];
    float cx = p[6], cy = p[7], cz = p[8];
    float e1x = cx - cax, e1y = cy - cay, e1z = cz - caz;
    float inv = rsqrtf(e1x * e1x + e1y * e1y + e1z * e1z + 1e-8f);
    e1x *= inv; e1y *= inv; e1z *= inv;
    float ux = nx - cax, uy = ny - cay, uz = nz - caz;
    float dt = ux * e1x + uy * e1y + uz * e1z;
    float e2x = ux - dt * e1x, e2y = uy - dt * e1y, e2z = uz - dt * e1z;
    inv = rsqrtf(e2x * e2x + e2y * e2y + e2z * e2z + 1e-8f);
    e2x *= inv; e2y *= inv; e2z *= inv;
    float e3x = e1y * e2z - e1z * e2y;
    float e3y = e1z * e2x - e1x * e2z;
    float e3z = e1x * e2y - e1y * e2x;
    R[0] = e1x; R[1] = e2x; R[2] = e3x;
    R[3] = e1y; R[4] = e2y; R[5] = e3y;
    R[6] = e1z; R[7] = e2z; R[8] = e3z;
}

__device__ __forceinline__ int lower_bound_i(const int* a, int n, int v) {
    int lo = 0, hi = n;
    while (lo < hi) { int mid = (lo + hi) >> 1; if (a[mid] < v) lo = mid + 1; else hi = mid; }
    return lo;
}

// ---------------- prep: localb + pair frags + Wt transposes + b2b + rcnt ----------------
// blocks: [0,2048) convb | [2048,2076) fmt | [2076,3404) fmt_wt | 3404 misc
__global__ __launch_bounds__(256) void prep_kernel(
    const float* __restrict__ local,
    const float* __restrict__ w_p1, const float* __restrict__ w_p2,
    const float* __restrict__ b_p2, const float* __restrict__ wb,
    const float* __restrict__ w_dist, const float* __restrict__ w_dir,
    const float* __restrict__ w_rot,
    const int* __restrict__ batch, const int* __restrict__ chain,
    const float* __restrict__ w0, const float* __restrict__ w1,
    const float* __restrict__ w2, const float* __restrict__ w3,
    const float* __restrict__ w4, const float* __restrict__ w5,
    const float* __restrict__ w6, const float* __restrict__ w7,
    const float* __restrict__ w8, const float* __restrict__ w9,
    const float* __restrict__ w10,
    ushort* __restrict__ localb, ushort* __restrict__ pf, ushort* __restrict__ wt,
    float* __restrict__ b2b, float* __restrict__ rcnt) {
    __shared__ ushort tile[32][33];
    int bid = blockIdx.x, tid = threadIdx.x;
    if (bid < 2048) {
        size_t i4 = ((size_t)bid * 256 + tid) * 4;
        float4 v = *(const float4*)&local[i4];
        *(uint2*)&localb[i4] = make_uint2(pk2(v.x, v.y), pk2(v.z, v.w));
    } else if (bid < 2076) {
        int u = (bid - 2048) * 256 + tid;
        uint* pfu = (uint*)pf;
        if (u < 4096) {
            int fs = u >> 8, rem = u & 255, lane = rem >> 2, jj = rem & 3;
            int hi = lane >> 4, lo = lane & 15;
            int f = fs >> 1, s = fs & 1;
            int k0 = 32 * s + hi * 8 + 2 * jj;
            int c = 16 * f + lo;
            pfu[u] = pk2(w_p1[k0 * 128 + c], w_p1[(k0 + 1) * 128 + c]);
        } else if (u < 5120) {
            int u2 = u - 4096;
            int s2 = u2 >> 8, rem = u2 & 255, lane = rem >> 2, jj = rem & 3;
            int hi = lane >> 4, lo = lane & 15;
            int c0 = 32 * s2 + 8 * hi + 2 * jj;
            float v0 = 0.f, v1 = 0.f;
            if (lo < 8) {
                for (int q = 0; q < 64; q++) {
                    float wbq = wb[q * 8 + lo];
                    v0 += w_p2[c0 * 64 + q] * wbq;
                    v1 += w_p2[(c0 + 1) * 64 + q] * wbq;
                }
            }
            pfu[u] = pk2(v0, v1);
        } else if (u < 7168) {
            int u2 = u - 5120;
            int fs = u2 >> 8, rem = u2 & 255, lane = rem >> 2, jj = rem & 3;
            int hi = lane >> 4, lo = lane & 15;
            int f = fs >> 1, s = fs & 1;
            int k0 = 32 * s + hi * 8 + 2 * jj;
            int c = 16 * f + lo;
            float v0 = (k0 < 16) ? w_dist[k0 * 64 + c] : (k0 < 31) ? w_dir[(k0 - 16) * 64 + c]
                     : (k0 < 43) ? w_rot[(k0 - 31) * 64 + c] : 0.f;
            int k1 = k0 + 1;
            float v1 = (k1 < 16) ? w_dist[k1 * 64 + c] : (k1 < 31) ? w_dir[(k1 - 16) * 64 + c]
                     : (k1 < 43) ? w_rot[(k1 - 31) * 64 + c] : 0.f;
            pfu[u] = pk2(v0, v1);
        }
    } else if (bid < 3404) {
        int fb = bid - 2076;
        const int zbase[12] = {0, 128, 256, 384, 512, 576, 640, 704, 1008, 1136, 1200, 1328};
        int z = 0;
        #pragma unroll
        for (int i = 0; i < 11; i++) if (fb >= zbase[i + 1]) z = i + 1;
        int loc = fb - zbase[z];
        const float* W; int K, N; size_t off;
        switch (z) {
            case 0:  W = w0;  K = 256; N = 512; off = 0;       break;
            case 1:  W = w1;  K = 256; N = 512; off = 131072;  break;
            case 2:  W = w2;  K = 256; N = 512; off = 262144;  break;
            case 3:  W = w3;  K = 256; N = 512; off = 393216;  break;
            case 4:  W = w4;  K = 256; N = 256; off = 524288;  break;
            case 5:  W = w5;  K = 256; N = 256; off = 589824;  break;
            case 6:  W = w6;  K = 256; N = 256; off = 655360;  break;
            case 7:  W = w7;  K = 608; N = 512; off = 720896;  break;
            case 8:  W = w8;  K = 512; N = 256; off = 1032192; break;
            case 9:  W = w9;  K = 256; N = 256; off = 1163264; break;
            default: W = w10; K = 512; N = 256; off = 1228800; break;
        }
        int nx = N >> 5;
        int bn = (loc % nx) * 32, bk = (loc / nx) * 32;
        int tx = tid & 31, ty = tid >> 5;
        #pragma unroll
        for (int i = 0; i < 32; i += 8)
            tile[ty + i][tx] = f2bf(W[(size_t)(bk + ty + i) * N + bn + tx]);
        __syncthreads();
        #pragma unroll
        for (int i = 0; i < 32; i += 8)
            wt[off + (size_t)(bn + ty + i) * K + bk + tx] = tile[tx][ty + i];
    } else {
        if (tid < 8) {
            float s = 0.f;
            for (int q = 0; q < 64; q++) s += b_p2[q] * wb[q * 8 + tid];
            b2b[tid] = s;
        } else if (tid < 40) {
            int seg = tid - 8;
            int lo = lower_bound_i(batch, NN, seg);
            int hi = lower_bound_i(batch, NN, seg + 1);
            rcnt[seg] = 1.f / fmaxf((float)(hi - lo), 1.f);
        } else if (tid < 104) {
            int seg = tid - 40;
            int lo = lower_bound_i(chain, NN, seg);
            int hi = lower_bound_i(chain, NN, seg + 1);
            rcnt[32 + seg] = 1.f / fmaxf((float)(hi - lo), 1.f);
        }
    }
}

// ---------------- raw pair features (inline frames) ----------------
__global__ __launch_bounds__(256) void pair_raw_kernel(
    const float* __restrict__ pos, const int* __restrict__ nbr,
    const int* __restrict__ resi, const int* __restrict__ chain,
    ushort* __restrict__ feat, int* __restrict__ relidx, ushort* __restrict__ tfb) {
    int p = blockIdx.x * 256 + threadIdx.x;
    int n = p >> 5, k = p & 31;
    int j = nbr[p];
    int same = (chain[j] == chain[n]);
    int off = min(max(resi[j] - resi[n], -32), 32) + 32;
    relidx[p] = same ? off : -1;

    float can0 = pos[n * 15 + 3], can1 = pos[n * 15 + 4], can2 = pos[n * 15 + 5];
    float cbn0 = pos[n * 15 + 12], cbn1 = pos[n * 15 + 13], cbn2 = pos[n * 15 + 14];
    float Rn[9], Rj[9];
    frames_of(pos + (size_t)n * 15, Rn);
    float pj[15];
    #pragma unroll
    for (int i = 0; i < 15; i++) pj[i] = pos[j * 15 + i];
    frames_of(pj, Rj);

    float fe[43];
    float d0 = pj[12] - cbn0, d1 = pj[13] - cbn1, d2 = pj[14] - cbn2;
    float dcb = sqrtf(d0 * d0 + d1 * d1 + d2 * d2 + 1e-8f);
    #pragma unroll
    for (int i = 0; i < 16; i++) {
        float c = (22.f / 15.f) * (float)i;
        float z = (dcb - c) * (1.f / 1.375f);
        fe[i] = __expf(-z * z);
    }
    #pragma unroll
    for (int a = 0; a < 5; a++) {
        float vx = pj[a * 3 + 0] - can0;
        float vy = pj[a * 3 + 1] - can1;
        float vz = pj[a * 3 + 2] - can2;
        float invv = rsqrtf(vx * vx + vy * vy + vz * vz + 1e-8f);
        fe[16 + a * 3 + 0] = vx * invv;
        fe[16 + a * 3 + 1] = vy * invv;
        fe[16 + a * 3 + 2] = vz * invv;
    }
    #pragma unroll
    for (int b = 0; b < 3; b++)
        #pragma unroll
        for (int c2 = 0; c2 < 3; c2++)
            fe[31 + b * 3 + c2] = Rn[0 + b] * Rj[0 + c2] + Rn[3 + b] * Rj[3 + c2] + Rn[6 + b] * Rj[6 + c2];
    float t0 = pj[3] - can0, t1 = pj[4] - can1, t2 = pj[5] - can2;
    #pragma unroll
    for (int b = 0; b < 3; b++)
        fe[40 + b] = Rn[0 + b] * t0 + Rn[3 + b] * t1 + Rn[6 + b] * t2;

    #pragma unroll
    for (int q = 0; q < 8; q++) {
        uint4 w;
        float v0 = (q * 8 + 0 < 43) ? fe[q * 8 + 0] : 0.f;
        float v1 = (q * 8 + 1 < 43) ? fe[q * 8 + 1] : 0.f;
        float v2 = (q * 8 + 2 < 43) ? fe[q * 8 + 2] : 0.f;
        float v3 = (q * 8 + 3 < 43) ? fe[q * 8 + 3] : 0.f;
        float v4 = (q * 8 + 4 < 43) ? fe[q * 8 + 4] : 0.f;
        float v5 = (q * 8 + 5 < 43) ? fe[q * 8 + 5] : 0.f;
        float v6 = (q * 8 + 6 < 43) ? fe[q * 8 + 6] : 0.f;
        float v7 = (q * 8 + 7 < 43) ? fe[q * 8 + 7] : 0.f;
        w.x = pk2(v0, v1); w.y = pk2(v2, v3); w.z = pk2(v4, v5); w.w = pk2(v6, v7);
        *(uint4*)&feat[(size_t)p * 64 + q * 8] = w;
    }
    float rt0 = fe[40], rt1 = fe[41], rt2 = fe[42];
    float dr2 = rt0 * rt0 + rt1 * rt1 + rt2 * rt2 + 1e-8f;
    float invdr = rsqrtf(dr2);
    float drel = dr2 * invdr;
    ushort* tf = tfb + (size_t)n * 608 + k * 19;
    #pragma unroll
    for (int i = 0; i < 16; i++) {
        float c = (22.f / 15.f) * (float)i;
        float z = (drel - c) * (1.f / 1.375f);
        tf[i] = f2bf(__expf(-z * z));
    }
    tf[16] = f2bf(rt0 * invdr);
    tf[17] = f2bf(rt1 * invdr);
    tf[18] = f2bf(rt2 * invdr);
}

// ---------------- fused pair: stage0 + relpos + LN + MLP + @W2B -> bias ----------------
__global__ __launch_bounds__(256) void pair_fused_kernel(
    const ushort* __restrict__ feat, const int* __restrict__ relidx,
    const float* __restrict__ w_relpos, const ushort* __restrict__ pf,
    const float* __restrict__ lng, const float* __restrict__ lnb,
    const float* __restrict__ b_p1, const float* __restrict__ b2b,
    float* __restrict__ bias) {
    __shared__ __align__(16) ushort hx[4 * 2048];
    int tid = threadIdx.x;
    int wid = tid >> 6, lane = tid & 63, hi = lane >> 4, lo = lane & 15;
    bf16x8 wf[8];
    #pragma unroll
    for (int fs = 0; fs < 8; fs++) wf[fs] = *(const bf16x8*)&pf[10240 + fs * 512 + lane * 8];
    bf16x8 w1f[16];
    #pragma unroll
    for (int fs = 0; fs < 16; fs++) w1f[fs] = *(const bf16x8*)&pf[fs * 512 + lane * 8];
    bf16x8 w2f[4];
    #pragma unroll
    for (int s2 = 0; s2 < 4; s2++) w2f[s2] = *(const bf16x8*)&pf[8192 + s2 * 512 + lane * 8];
    float sg_r[4][4], sbt_r[4][4];
    #pragma unroll
    for (int f = 0; f < 4; f++)
        #pragma unroll
        for (int r = 0; r < 4; r++) {
            int c = 16 * f + 4 * hi + r;
            sg_r[f][r] = lng[c];
            sbt_r[f][r] = lnb[c];
        }
    float b2b_r[4];
    #pragma unroll
    for (int r = 0; r < 4; r++) b2b_r[r] = (hi < 2) ? b2b[4 * hi + r] : 0.f;
    float sb1_r[8][4];
    #pragma unroll
    for (int f = 0; f < 8; f++)
        #pragma unroll
        for (int r = 0; r < 4; r++) sb1_r[f][r] = b_p1[16 * f + 4 * hi + r];

    ushort* hxw = &hx[wid * 2048];
    const f32x4 zz = {0.f, 0.f, 0.f, 0.f};
    for (int t = blockIdx.x * 4 + wid; t < (NN * KK / 16); t += 16384) {
        int r0 = t << 4;
        bf16x8 bp0 = *(const bf16x8*)(feat + (size_t)(r0 + lo) * 64 + hi * 8);
        bf16x8 bp1 = *(const bf16x8*)(feat + (size_t)(r0 + lo) * 64 + 32 + hi * 8);
        // stage0
        f32x4 a0f[4];
        #pragma unroll
        for (int f = 0; f < 4; f++) {
            a0f[f] = __builtin_amdgcn_mfma_f32_16x16x32_bf16(wf[f * 2 + 0], bp0, zz, 0, 0, 0);
            a0f[f] = __builtin_amdgcn_mfma_f32_16x16x32_bf16(wf[f * 2 + 1], bp1, a0f[f], 0, 0, 0);
        }
        int ridx = relidx[r0 + lo];
        float val[4][4];
        float part = 0.f;
        #pragma unroll
        for (int f = 0; f < 4; f++)
            #pragma unroll
            for (int r = 0; r < 4; r++) {
                int c = 16 * f + 4 * hi + r;
                float rv = (ridx >= 0) ? w_relpos[ridx * 64 + c] : 0.f;
                float v = a0f[f][r] + rv;
                val[f][r] = v;
                part += v;
            }
        part += __shfl_xor(part, 16);
        part += __shfl_xor(part, 32);
        float mean = part * (1.f / 64.f);
        float v2 = 0.f;
        #pragma unroll
        for (int f = 0; f < 4; f++)
            #pragma unroll
            for (int r = 0; r < 4; r++) {
                float dv = val[f][r] - mean;
                val[f][r] = dv;
                v2 += dv * dv;
            }
        v2 += __shfl_xor(v2, 16);
        v2 += __shfl_xor(v2, 32);
        float rs = rsqrtf(v2 * (1.f / 64.f) + 1e-5f);
        // P exchange via per-wave LDS tile [16][64] (XOR-swizzled)
        #pragma unroll
        for (int f = 0; f < 4; f++) {
            int c0 = 16 * f + 4 * hi;
            float v0 = val[f][0] * rs * sg_r[f][0] + sbt_r[f][0];
            float v1 = val[f][1] * rs * sg_r[f][1] + sbt_r[f][1];
            float v2b = val[f][2] * rs * sg_r[f][2] + sbt_r[f][2];
            float v3 = val[f][3] * rs * sg_r[f][3] + sbt_r[f][3];
            int idx = (lo * 64 + c0) ^ ((lo & 7) << 3);
            *(uint2*)&hxw[idx] = make_uint2(pk2(v0, v1), pk2(v2b, v3));
        }
        bf16x8 bh0 = *(const bf16x8*)&hxw[(lo * 64 + 0 + hi * 8) ^ ((lo & 7) << 3)];
        bf16x8 bh1 = *(const bf16x8*)&hxw[(lo * 64 + 32 + hi * 8) ^ ((lo & 7) << 3)];
        // stage1: 64 -> 128 + gelu -> H tile [16][128]
        #pragma unroll
        for (int f = 0; f < 8; f++) {
            f32x4 acch = __builtin_amdgcn_mfma_f32_16x16x32_bf16(w1f[f * 2 + 0], bh0, zz, 0, 0, 0);
            acch = __builtin_amdgcn_mfma_f32_16x16x32_bf16(w1f[f * 2 + 1], bh1, acch, 0, 0, 0);
            int c0 = 16 * f + 4 * hi;
            float v0 = gelu_f(acch[0] + sb1_r[f][0]);
            float v1 = gelu_f(acch[1] + sb1_r[f][1]);
            float v2b = gelu_f(acch[2] + sb1_r[f][2]);
            float v3 = gelu_f(acch[3] + sb1_r[f][3]);
            int idx = (lo * 128 + c0) ^ ((lo & 7) << 3);
            *(uint2*)&hxw[idx] = make_uint2(pk2(v0, v1), pk2(v2b, v3));
        }
        // stage2: 128 -> 8
        f32x4 acc = zz;
        #pragma unroll
        for (int s2 = 0; s2 < 4; s2++) {
            int idx = (lo * 128 + 32 * s2 + 8 * hi) ^ ((lo & 7) << 3);
            bf16x8 bh = *(const bf16x8*)&hxw[idx];
            acc = __builtin_amdgcn_mfma_f32_16x16x32_bf16(w2f[s2], bh, acc, 0, 0, 0);
        }
        if (hi < 2) {
            int n = r0 >> 5, kb = (r0 & 31) + lo;
            #pragma unroll
            for (int r = 0; r < 4; r++)
                bias[(size_t)n * 256 + (4 * hi + r) * 32 + kb] = acc[r] + b2b_r[r];
        }
    }
}

// ---------------- GEMM core T (BM=128, BN=128) ----------------
__device__ __forceinline__ void gemm_coreT(
    const ushort* __restrict__ A, const ushort* __restrict__ Wt,
    int K, int row0, int colW0, int tid,
    ushort* sA, ushort* sB, f32x4 acc[4][4]) {
    int wid = tid >> 6, lane = tid & 63, lo = lane & 15, hi = lane >> 4;
    int wr = wid >> 1, wc = wid & 1;
    int ar = tid >> 1, akh = (tid & 1) * 16;
    for (int kt = 0; kt < K; kt += 32) {
        const ushort* ap = &A[(size_t)(row0 + ar) * K + kt + akh];
        uint4 a01 = *(const uint4*)ap;
        uint4 a23 = *(const uint4*)(ap + 8);
        const ushort* bp = &Wt[(size_t)(colW0 + ar) * K + kt + akh];
        uint4 b01 = *(const uint4*)bp;
        uint4 b23 = *(const uint4*)(bp + 8);
        __syncthreads();
        *(uint4*)&sA[ar * 40 + akh] = a01;
        *(uint4*)&sA[ar * 40 + akh + 8] = a23;
        *(uint4*)&sB[ar * 40 + akh] = b01;
        *(uint4*)&sB[ar * 40 + akh + 8] = b23;
        __syncthreads();
        bf16x8 af[4], bfr[4];
        #pragma unroll
        for (int mi = 0; mi < 4; mi++) af[mi] = *(const bf16x8*)&sA[(wr * 64 + mi * 16 + lo) * 40 + hi * 8];
        #pragma unroll
        for (int ni = 0; ni < 4; ni++) bfr[ni] = *(const bf16x8*)&sB[(wc * 64 + ni * 16 + lo) * 40 + hi * 8];
        #pragma unroll
        for (int mi = 0; mi < 4; mi++)
            #pragma unroll
            for (int ni = 0; ni < 4; ni++)
                acc[mi][ni] = __builtin_amdgcn_mfma_f32_16x16x32_bf16(af[mi], bfr[ni], acc[mi][ni], 0, 0, 0);
    }
}

// ---------------- t1 GEMM ----------------
__global__ __launch_bounds__(256) void gemm_t1T(
    const ushort* __restrict__ A, const ushort* __restrict__ Wt, ushort* __restrict__ C,
    int K, int Nc) {
    __shared__ __align__(16) ushort sA[128 * 40];
    __shared__ __align__(16) ushort sB[128 * 40];
    int row0 = blockIdx.y * 128, col0 = blockIdx.x * 128;
    int tid = threadIdx.x;
    const f32x4 zz = {0.f, 0.f, 0.f, 0.f};
    f32x4 acc[4][4] = {{zz, zz, zz, zz}, {zz, zz, zz, zz}, {zz, zz, zz, zz}, {zz, zz, zz, zz}};
    gemm_coreT(A, Wt, K, row0, col0, tid, sA, sB, acc);
    int wid = tid >> 6, lane = tid & 63, lo = lane & 15, hi = lane >> 4;
    int wr = wid >> 1, wc = wid & 1;
    #pragma unroll
    for (int ni = 0; ni < 4; ni++) {
        int col = col0 + wc * 64 + ni * 16 + lo;
        #pragma unroll
        for (int mi = 0; mi < 4; mi++) {
            #pragma unroll
            for (int r = 0; r < 4; r++) {
                int row = row0 + wr * 64 + mi * 16 + hi * 4 + r;
                C[(size_t)row * Nc + col] = f2bf(gelu_f(acc[mi][ni][r]));
            }
        }
    }
}

// ---------------- small-tile GEMM (BM=64, BN=64) ----------------
__global__ __launch_bounds__(256) void gemm_n64s(
    const ushort* __restrict__ A, const ushort* __restrict__ Wt, float* __restrict__ C,
    int K, int Nc, const float* __restrict__ bias, const float* __restrict__ addp) {
    __shared__ __align__(16) ushort sA[64 * 40];
    __shared__ __align__(16) ushort sB[64 * 40];
    int row0 = blockIdx.y * 64, col0 = blockIdx.x * 64;
    int tid = threadIdx.x;
    int wid = tid >> 6, lane = tid & 63, lo = lane & 15, hi = lane >> 4;
    int wr = wid >> 1, wc = wid & 1;
    int ar = tid >> 2, akh = (tid & 3) * 8;
    const f32x4 zz = {0.f, 0.f, 0.f, 0.f};
    f32x4 acc[2][2] = {{zz, zz}, {zz, zz}};
    for (int kt = 0; kt < K; kt += 32) {
        uint4 a0 = *(const uint4*)&A[(size_t)(row0 + ar) * K + kt + akh];
        uint4 b0 = *(const uint4*)&Wt[(size_t)(col0 + ar) * K + kt + akh];
        __syncthreads();
        *(uint4*)&sA[ar * 40 + akh] = a0;
        *(uint4*)&sB[ar * 40 + akh] = b0;
        __syncthreads();
        bf16x8 af[2], bfr[2];
        #pragma unroll
        for (int mi = 0; mi < 2; mi++) af[mi] = *(const bf16x8*)&sA[(wr * 32 + mi * 16 + lo) * 40 + hi * 8];
        #pragma unroll
        for (int ni = 0; ni < 2; ni++) bfr[ni] = *(const bf16x8*)&sB[(wc * 32 + ni * 16 + lo) * 40 + hi * 8];
        #pragma unroll
        for (int mi = 0; mi < 2; mi++)
            #pragma unroll
            for (int ni = 0; ni < 2; ni++)
                acc[mi][ni] = __builtin_amdgcn_mfma_f32_16x16x32_bf16(af[mi], bfr[ni], acc[mi][ni], 0, 0, 0);
    }
    #pragma unroll
    for (int ni = 0; ni < 2; ni++) {
        int col = col0 + wc * 32 + ni * 16 + lo;
        float bc = bias ? bias[col] : 0.f;
        #pragma unroll
        for (int mi = 0; mi < 2; mi++) {
            #pragma unroll
            for (int r = 0; r < 4; r++) {
                int row = row0 + wr * 32 + mi * 16 + hi * 4 + r;
                float v = acc[mi][ni][r] + bc;
                if (addp) v += addp[(size_t)row * Nc + col];
                C[(size_t)row * Nc + col] = v;
            }
        }
    }
}

// ---------------- fused QKV GEMM T ----------------
__global__ __launch_bounds__(256) void gemm_qkvT(
    const ushort* __restrict__ A, const ushort* __restrict__ Wt3,
    float* __restrict__ qb, ushort* __restrict__ kb, ushort* __restrict__ vb) {
    __shared__ __align__(16) ushort sA[128 * 40];
    __shared__ __align__(16) ushort sB[128 * 40];
    int row0 = blockIdx.y * 128, col0 = blockIdx.x * 128;
    int wsel = col0 >> 8, colW = col0 & 255;
    int tid = threadIdx.x;
    const f32x4 zz = {0.f, 0.f, 0.f, 0.f};
    f32x4 acc[4][4] = {{zz, zz, zz, zz}, {zz, zz, zz, zz}, {zz, zz, zz, zz}, {zz, zz, zz, zz}};
    gemm_coreT(A, Wt3, 256, row0, col0, tid, sA, sB, acc);
    int wid = tid >> 6, lane = tid & 63, lo = lane & 15, hi = lane >> 4;
    int wr = wid >> 1, wc = wid & 1;
    #pragma unroll
    for (int ni = 0; ni < 4; ni++) {
        int colo = colW + wc * 64 + ni * 16 + lo;
        #pragma unroll
        for (int mi = 0; mi < 4; mi++) {
            #pragma unroll
            for (int r = 0; r < 4; r++) {
                int row = row0 + wr * 64 + mi * 16 + hi * 4 + r;
                float v = acc[mi][ni][r];
                if (wsel == 0) qb[(size_t)row * 256 + colo] = v;
                else if (wsel == 1) kb[(size_t)row * 256 + colo] = f2bf(v);
                else vb[(size_t)row * 256 + colo] = f2bf(v);
            }
        }
    }
}

// ---------------- fused FFN GEMM T ----------------
__global__ __launch_bounds__(256) void gemm_ffnT(
    const ushort* __restrict__ A, const ushort* __restrict__ Wt4,
    ushort* __restrict__ o0, ushort* __restrict__ o1,
    ushort* __restrict__ o2, ushort* __restrict__ o3) {
    __shared__ __align__(16) ushort sA[128 * 40];
    __shared__ __align__(16) ushort sB[128 * 40];
    int row0 = blockIdx.y * 128, col0 = blockIdx.x * 128;
    int wsel = col0 >> 9, colW = col0 & 511;
    ushort* O = (wsel == 0) ? o0 : (wsel == 1) ? o1 : (wsel == 2) ? o2 : o3;
    int tid = threadIdx.x;
    const f32x4 zz = {0.f, 0.f, 0.f, 0.f};
    f32x4 acc[4][4] = {{zz, zz, zz, zz}, {zz, zz, zz, zz}, {zz, zz, zz, zz}, {zz, zz, zz, zz}};
    gemm_coreT(A, Wt4, 256, row0, col0, tid, sA, sB, acc);
    int wid = tid >> 6, lane = tid & 63, lo = lane & 15, hi = lane >> 4;
    int wr = wid >> 1, wc = wid & 1;
    #pragma unroll
    for (int ni = 0; ni < 4; ni++) {
        int colo = colW + wc * 64 + ni * 16 + lo;
        #pragma unroll
        for (int mi = 0; mi < 4; mi++) {
            #pragma unroll
            for (int r = 0; r < 4; r++) {
                int row = row0 + wr * 64 + mi * 16 + hi * 4 + r;
                float v = acc[mi][ni][r];
                if (wsel > 0) v = gelu_f(v);
                O[(size_t)row * 512 + colo] = f2bf(v);
            }
        }
    }
}

// ---------------- attention ----------------
__global__ __launch_bounds__(256) void attn_kernel(
    const float* __restrict__ q, const ushort* __restrict__ kp, const ushort* __restrict__ vp,
    const float* __restrict__ bias, const int* __restrict__ nbr, ushort* __restrict__ o) {
    int n = blockIdx.x;
    __shared__ float qs[256];
    __shared__ int js[32];
    __shared__ float ls[256];
    __shared__ __align__(16) uint4 vs[32 * 33];
    int t = threadIdx.x;
    qs[t] = q[(size_t)n * 256 + t];
    if (t < 32) js[t] = nbr[n * 32 + t];
    __syncthreads();
    int vrow = t >> 3, vseg = t & 7;
    const uint4* vsrc = (const uint4*)(vp + (size_t)js[vrow] * 256);
    uint4 vr0 = vsrc[vseg * 4 + 0];
    uint4 vr1 = vsrc[vseg * 4 + 1];
    uint4 vr2 = vsrc[vseg * 4 + 2];
    uint4 vr3 = vsrc[vseg * 4 + 3];
    int h = t >> 5, k = t & 31;
    int j = js[k];
    const bf16x8* kr = (const bf16x8*)(kp + (size_t)j * 256 + h * 32);
    bf16x8 kv0 = kr[0], kv1 = kr[1], kv2 = kr[2], kv3 = kr[3];
    const float* qh = qs + h * 32;
    float dot = 0.f;
    #pragma unroll
    for (int i = 0; i < 8; i++) dot += qh[i] * bf2f((ushort)kv0[i]);
    #pragma unroll
    for (int i = 0; i < 8; i++) dot += qh[8 + i] * bf2f((ushort)kv1[i]);
    #pragma unroll
    for (int i = 0; i < 8; i++) dot += qh[16 + i] * bf2f((ushort)kv2[i]);
    #pragma unroll
    for (int i = 0; i < 8; i++) dot += qh[24 + i] * bf2f((ushort)kv3[i]);
    float l = dot * 0.17677669529663687f + bias[(size_t)n * 256 + t];
    float mx = l;
    #pragma unroll
    for (int m = 16; m > 0; m >>= 1) mx = fmaxf(mx, __shfl_xor(mx, m));
    float e = __expf(l - mx);
    float sum = e;
    #pragma unroll
    for (int m = 16; m > 0; m >>= 1) sum += __shfl_xor(sum, m);
    ls[t] = e / sum;
    vs[vrow * 33 + vseg * 4 + 0] = vr0;
    vs[vrow * 33 + vseg * 4 + 1] = vr1;
    vs[vrow * 33 + vseg * 4 + 2] = vr2;
    vs[vrow * 33 + vseg * 4 + 3] = vr3;
    __syncthreads();
    const ushort* vsu = (const ushort*)vs;
    const float* lh = ls + h * 32;
    float acc = 0.f;
    #pragma unroll
    for (int kk = 0; kk < 32; kk++)
        acc += lh[kk] * bf2f(vsu[kk * 264 + h * 32 + k]);
    o[(size_t)n * 256 + t] = f2bf(acc);
}

// ---------------- LN(a+b) ----------------
__global__ __launch_bounds__(256) void ln_add_kernel(
    const float* __restrict__ a, const float* __restrict__ b,
    const float* __restrict__ g, const float* __restrict__ be,
    float* __restrict__ xout, ushort* __restrict__ xbout, float* __restrict__ sout) {
    int row = blockIdx.x * 4 + (threadIdx.x >> 6);
    int lane = threadIdx.x & 63;
    size_t base = (size_t)row * 256 + lane * 4;
    float4 av = *(const float4*)(a + base);
    float4 bv = *(const float4*)(b + base);
    float s0 = av.x + bv.x, s1 = av.y + bv.y, s2 = av.z + bv.z, s3 = av.w + bv.w;
    float sum = wave_sum64(s0 + s1 + s2 + s3);
    float mean = sum * (1.f / 256.f);
    float d0 = s0 - mean, d1 = s1 - mean, d2 = s2 - mean, d3 = s3 - mean;
    float v = wave_sum64(d0 * d0 + d1 * d1 + d2 * d2 + d3 * d3);
    float rs = rsqrtf(v * (1.f / 256.f) + 1e-5f);
    float4 gv = *(const float4*)(g + lane * 4);
    float4 bev = *(const float4*)(be + lane * 4);
    float4 xo;
    xo.x = d0 * rs * gv.x + bev.x;
    xo.y = d1 * rs * gv.y + bev.y;
    xo.z = d2 * rs * gv.z + bev.z;
    xo.w = d3 * rs * gv.w + bev.w;
    *(float4*)(xout + base) = xo;
    *(uint2*)(xbout + base) = make_uint2(pk2(xo.x, xo.y), pk2(xo.z, xo.w));
    float4 so; so.x = s0; so.y = s1; so.z = s2; so.w = s3;
    *(float4*)(sout + base) = so;
}

// ---------------- segment partial sums ----------------
__global__ __launch_bounds__(256) void seg_partial_kernel(
    const ushort* __restrict__ up, const int* __restrict__ batch, const int* __restrict__ chain,
    float* __restrict__ mb_acc, float* __restrict__ mc_acc) {
    int r0 = blockIdx.x * 32;
    int t = threadIdx.x;
    float ab0 = 0.f, ab1 = 0.f, ac0 = 0.f, ac1 = 0.f;
    int curb = batch[r0], curc = chain[r0];
    for (int r = r0; r < r0 + 32; r++) {
        int b = batch[r], c = chain[r];
        if (b != curb) {
            atomicAdd(&mb_acc[curb * 512 + t], ab0);
            atomicAdd(&mb_acc[curb * 512 + 256 + t], ab1);
            ab0 = ab1 = 0.f; curb = b;
        }
        if (c != curc) {
            atomicAdd(&mc_acc[curc * 512 + t], ac0);
            atomicAdd(&mc_acc[curc * 512 + 256 + t], ac1);
            ac0 = ac1 = 0.f; curc = c;
        }
        float v0 = bf2f(up[(size_t)r * 512 + t]);
        float v1 = bf2f(up[(size_t)r * 512 + 256 + t]);
        ab0 += v0; ab1 += v1; ac0 += v0; ac1 += v1;
    }
    atomicAdd(&mb_acc[curb * 512 + t], ab0);
    atomicAdd(&mb_acc[curb * 512 + 256 + t], ab1);
    atomicAdd(&mc_acc[curc * 512 + t], ac0);
    atomicAdd(&mc_acc[curc * 512 + 256 + t], ac1);
}

// ---------------- hidden combine (raw sums * rcnt) ----------------
__global__ __launch_bounds__(256) void hidden_kernel(
    const ushort* __restrict__ up, const ushort* __restrict__ cg, const ushort* __restrict__ bg,
    ushort* __restrict__ lg, const float* __restrict__ mb, const float* __restrict__ mc,
    const int* __restrict__ batch, const int* __restrict__ chain,
    const float* __restrict__ rcnt) {
    size_t e4 = ((size_t)blockIdx.x * 256 + threadIdx.x) * 4;
    int n = (int)(e4 >> 9), d = (int)(e4 & 511);
    float rb = rcnt[batch[n]];
    float rc = rcnt[32 + chain[n]];
    float4 mbv = *(const float4*)&mb[batch[n] * 512 + d];
    float4 mcv = *(const float4*)&mc[chain[n] * 512 + d];
    uint2 u_up = *(const uint2*)&up[e4];
    uint2 u_cg = *(const uint2*)&cg[e4];
    uint2 u_bg = *(const uint2*)&bg[e4];
    uint2 u_lg = *(const uint2*)&lg[e4];
    float h0 = bf2f((ushort)u_bg.x) * (mbv.x * rb) + bf2f((ushort)u_cg.x) * (mcv.x * rc)
             + bf2f((ushort)u_lg.x) * bf2f((ushort)u_up.x);
    float h1 = bf2f((ushort)(u_bg.x >> 16)) * (mbv.y * rb) + bf2f((ushort)(u_cg.x >> 16)) * (mcv.y * rc)
             + bf2f((ushort)(u_lg.x >> 16)) * bf2f((ushort)(u_up.x >> 16));
    float h2 = bf2f((ushort)u_bg.y) * (mbv.z * rb) + bf2f((ushort)u_cg.y) * (mcv.z * rc)
             + bf2f((ushort)u_lg.y) * bf2f((ushort)u_up.y);
    float h3 = bf2f((ushort)(u_bg.y >> 16)) * (mbv.w * rb) + bf2f((ushort)(u_cg.y >> 16)) * (mcv.w * rc)
             + bf2f((ushort)(u_lg.y >> 16)) * bf2f((ushort)(u_up.y >> 16));
    *(uint2*)&lg[e4] = make_uint2(pk2(h0, h1), pk2(h2, h3));
}

// ---------------- final ----------------
__global__ __launch_bounds__(256) void final_kernel(
    const float* __restrict__ x1, const float* __restrict__ y2, const float* __restrict__ inc1,
    const float* __restrict__ ug, const float* __restrict__ ub,
    const float* __restrict__ fg, const float* __restrict__ fb, float* __restrict__ out) {
    int row = blockIdx.x * 4 + (threadIdx.x >> 6);
    int lane = threadIdx.x & 63;
    size_t base = (size_t)row * 256 + lane * 4;
    float4 xv = *(const float4*)(x1 + base);
    float4 yv = *(const float4*)(y2 + base);
    float4 iv = *(const float4*)(inc1 + base);
    float s0 = xv.x + yv.x, s1 = xv.y + yv.y, s2 = xv.z + yv.z, s3 = xv.w + yv.w;
    float t0 = iv.x + yv.x, t1 = iv.y + yv.y, t2 = iv.z + yv.z, t3 = iv.w + yv.w;
    float sums = wave_sum64(s0 + s1 + s2 + s3);
    float means = sums * (1.f / 256.f);
    float sd0 = s0 - means, sd1 = s1 - means, sd2 = s2 - means, sd3 = s3 - means;
    float vs = wave_sum64(sd0 * sd0 + sd1 * sd1 + sd2 * sd2 + sd3 * sd3);
    float rss = rsqrtf(vs * (1.f / 256.f) + 1e-5f);
    float sumt = wave_sum64(t0 + t1 + t2 + t3);
    float meant = sumt * (1.f / 256.f);
    float td0 = t0 - meant, td1 = t1 - meant, td2 = t2 - meant, td3 = t3 - meant;
    float vt = wave_sum64(td0 * td0 + td1 * td1 + td2 * td2 + td3 * td3);
    float rst = rsqrtf(vt * (1.f / 256.f) + 1e-5f);
    float4 ugv = *(const float4*)(ug + lane * 4);
    float4 ubv = *(const float4*)(ub + lane * 4);
    float4 fgv = *(const float4*)(fg + lane * 4);
    float4 fbv = *(const float4*)(fb + lane * 4);
    float4 ov;
    ov.x = (sd0 * rss * ugv.x + ubv.x) + (td0 * rst * fgv.x + fbv.x);
    ov.y = (sd1 * rss * ugv.y + ubv.y) + (td1 * rst * fgv.y + fbv.y);
    ov.z = (sd2 * rss * ugv.z + ubv.z) + (td2 * rst * fgv.z + fbv.z);
    ov.w = (sd3 * rss * ugv.w + ubv.w) + (td3 * rst * fgv.w + fbv.w);
    *(float4*)(out + base) = ov;
}

// ---------------- launch ----------------
extern "C" void kernel_launch(void* const* d_in, const int* in_sizes, int n_in,
                              void* d_out, int out_size, void* d_ws, size_t ws_size,
                              hipStream_t stream) {
    const float* local    = (const float*)d_in[0];
    const float* pos      = (const float*)d_in[1];
    const int*   nbr      = (const int*)d_in[2];
    const int*   resi     = (const int*)d_in[3];
    const int*   chain    = (const int*)d_in[4];
    const int*   batch    = (const int*)d_in[5];
    const float* w_relpos = (const float*)d_in[7];
    const float* w_dist   = (const float*)d_in[8];
    const float* w_dir    = (const float*)d_in[9];
    const float* w_rot    = (const float*)d_in[10];
    const float* ln_pair_g = (const float*)d_in[11];
    const float* ln_pair_b = (const float*)d_in[12];
    const float* w_p1     = (const float*)d_in[13];
    const float* b_p1     = (const float*)d_in[14];
    const float* w_p2     = (const float*)d_in[15];
    const float* b_p2     = (const float*)d_in[16];
    const float* wq       = (const float*)d_in[17];
    const float* wk       = (const float*)d_in[18];
    const float* wv       = (const float*)d_in[19];
    const float* wb       = (const float*)d_in[20];
    const float* wo       = (const float*)d_in[21];
    const float* ln_a_g   = (const float*)d_in[22];
    const float* ln_a_b   = (const float*)d_in[23];
    const float* w_t1     = (const float*)d_in[24];
    const float* w_t2     = (const float*)d_in[25];
    const float* w_up     = (const float*)d_in[26];
    const float* w_lg     = (const float*)d_in[27];
    const float* w_cg     = (const float*)d_in[28];
    const float* w_bg     = (const float*)d_in[29];
    const float* w_out    = (const float*)d_in[30];
    const float* b_out    = (const float*)d_in[31];
    const float* ln_u_g   = (const float*)d_in[32];
    const float* ln_u_b   = (const float*)d_in[33];
    const float* ln_f_g   = (const float*)d_in[34];
    const float* ln_f_b   = (const float*)d_in[35];

    float* ws = (float*)d_ws;
    float* biasb     = ws + 73728;         // -> 2170880
    float* tfeat_out = ws + 2170880;       // -> 4268032
    float* x1        = ws + 4268032;       // -> 6365184
    float* inc1      = ws + 6365184;       // -> 8462336
    ushort* featb    = (ushort*)(ws + 8462336);  // -> 16850944
    int* relidx      = (int*)(ws + 16850944);    // -> 17113088
    ushort* tfb      = (ushort*)(ws + 17113088); // -> 19603456
    ushort* wt       = (ushort*)(ws + 19603456); // -> 20283392
    ushort* x1b      = (ushort*)(ws + 20283392); // -> 21331968
    ushort* localb   = (ushort*)(ws + 21331968); // -> 22380544
    ushort* tmp512u  = (ushort*)(ws + 22380544); // -> 24477696
    float* y2        = ws + 22380544;      // over tmp512u after t2 consumed
    float* yb        = ws + 17113088;      // over tfb after t1 consumed
    float* qb        = ws + 8462336;       // phase 2 over featb (featb read-only, consumed)
    ushort* kbu      = (ushort*)(ws + 10559488);
    ushort* vbu      = (ushort*)(ws + 11608064);
    ushort* obu      = (ushort*)(ws + 12656640);
    ushort* upbu     = (ushort*)(ws + 8462336);  // phase 3
    ushort* lgbu     = (ushort*)(ws + 10559488);
    ushort* cgbu     = (ushort*)(ws + 12656640);
    ushort* bgbu     = (ushort*)(ws + 14753792);
    float* mb        = ws + 24477696;
    float* mc        = ws + 24494080;
    ushort* pfmt     = (ushort*)(ws + 24526848);
    float* b2b       = ws + 24535040;
    float* rcnt      = ws + 24535048;      // 96 floats

    prep_kernel<<<3405, 256, 0, stream>>>(local, w_p1, w_p2, b_p2, wb,
                                          w_dist, w_dir, w_rot, batch, chain,
                                          w_up, w_lg, w_cg, w_bg, wq, wk, wv,
                                          w_t1, w_t2, wo, w_out,
                                          localb, pfmt, wt, b2b, rcnt);
    pair_raw_kernel<<<NN * KK / 256, 256, 0, stream>>>(pos, nbr, resi, chain,
                                                       featb, relidx, tfb);
    pair_fused_kernel<<<4096, 256, 0, stream>>>(featb, relidx, w_relpos, pfmt,
                                                ln_pair_g, ln_pair_b, b_p1, b2b, biasb);
    // tfeat MLP
    gemm_t1T<<<dim3(4, 64), 256, 0, stream>>>(tfb, wt + 720896, tmp512u, 608, 512);
    gemm_n64s<<<dim3(4, 128), 256, 0, stream>>>(tmp512u, wt + 1032192, tfeat_out, 512, 256,
                                                nullptr, nullptr);
    // qkv
    gemm_qkvT<<<dim3(6, 64), 256, 0, stream>>>(localb, wt + 524288, qb, kbu, vbu);
    attn_kernel<<<NN, 256, 0, stream>>>(qb, kbu, vbu, biasb, nbr, obu);
    gemm_n64s<<<dim3(4, 128), 256, 0, stream>>>(obu, wt + 1163264, yb, 256, 256,
                                                nullptr, nullptr);
    ln_add_kernel<<<NN / 4, 256, 0, stream>>>(local, yb, ln_a_g, ln_a_b, x1, x1b, inc1);
    // FFN
    gemm_ffnT<<<dim3(16, 64), 256, 0, stream>>>(x1b, wt, upbu, lgbu, cgbu, bgbu);
    (void)hipMemsetAsync(mb, 0, (NBATCH + NCHAIN) * 512 * sizeof(float), stream);
    seg_partial_kernel<<<NN / 32, 256, 0, stream>>>(upbu, batch, chain, mb, mc);
    hidden_kernel<<<NN * 512 / 1024, 256, 0, stream>>>(upbu, cgbu, bgbu, lgbu, mb, mc,
                                                       batch, chain, rcnt);
    gemm_n64s<<<dim3(4, 128), 256, 0, stream>>>(lgbu, wt + 1228800, y2, 512, 256,
                                                b_out, tfeat_out);
    final_kernel<<<NN / 4, 256, 0, stream>>>(x1, y2, inc1, ln_u_g, ln_u_b, ln_f_g, ln_f_b, (float*)d_out);
}

// Round 16
// 251.041 us; speedup vs baseline: 1.1053x; 1.1053x over previous
//
#include <hip/hip_runtime.h>
#include <math.h>

#define NN 8192
#define KK 32
#define DD 256
#define PP 64
#define HH 8
#define DHH 32
#define NBATCH 32
#define NCHAIN 64

typedef __attribute__((ext_vector_type(8))) short bf16x8;
typedef __attribute__((ext_vector_type(4))) float f32x4;

// ---------------- helpers ----------------
__device__ __forceinline__ float gelu_f(float x) {
    float x3 = x * x * x;
    float e = __expf(fmaf(x3, -0.07135481f, x * -1.59576912f));
    return __fdividef(x, 1.f + e);
}

__device__ __forceinline__ float wave_sum64(float v) {
    #pragma unroll
    for (int m = 32; m > 0; m >>= 1) v += __shfl_xor(v, m);
    return v;
}

__device__ __forceinline__ ushort f2bf(float x) {
    union { float f; unsigned int u; } v; v.f = x;
    unsigned int r = v.u + 0x7fffu + ((v.u >> 16) & 1u);
    return (ushort)(r >> 16);
}

__device__ __forceinline__ float bf2f(ushort u) {
    union { unsigned int u; float f; } v; v.u = ((unsigned int)u) << 16;
    return v.f;
}

__device__ __forceinline__ uint pk2(float a, float b) {
    return (uint)f2bf(a) | ((uint)f2bf(b) << 16);
}

__device__ __forceinline__ void frames_of(const float* __restrict__ p, float R[9]) {
    float nx = p[0], ny = p[1], nz = p[2];
    float cax = p[3], cay = p[4], caz = p[5];
    float cx = p[6], cy = p[7], cz = p[8];
    float e1x = cx - cax, e1y = cy - cay, e1z = cz - caz;
    float inv = rsqrtf(e1x * e1x + e1y * e1y + e1z * e1z + 1e-8f);
    e1x *= inv; e1y *= inv; e1z *= inv;
    float ux = nx - cax, uy = ny - cay, uz = nz - caz;
    float dt = ux * e1x + uy * e1y + uz * e1z;
    float e2x = ux - dt * e1x, e2y = uy - dt * e1y, e2z = uz - dt * e1z;
    inv = rsqrtf(e2x * e2x + e2y * e2y + e2z * e2z + 1e-8f);
    e2x *= inv; e2y *= inv; e2z *= inv;
    float e3x = e1y * e2z - e1z * e2y;
    float e3y = e1z * e2x - e1x * e2z;
    float e3z = e1x * e2y - e1y * e2x;
    R[0] = e1x; R[1] = e2x; R[2] = e3x;
    R[3] = e1y; R[4] = e2y; R[5] = e3y;
    R[6] = e1z; R[7] = e2z; R[8] = e3z;
}

__device__ __forceinline__ int lower_bound_i(const int* a, int n, int v) {
    int lo = 0, hi = n;
    while (lo < hi) { int mid = (lo + hi) >> 1; if (a[mid] < v) lo = mid + 1; else hi = mid; }
    return lo;
}

// ---------------- prep: localb + pair frags + Wt transposes + b2b + rcnt ----------------
__global__ __launch_bounds__(256) void prep_kernel(
    const float* __restrict__ local,
    const float* __restrict__ w_p1, const float* __restrict__ w_p2,
    const float* __restrict__ b_p2, const float* __restrict__ wb,
    const float* __restrict__ w_dist, const float* __restrict__ w_dir,
    const float* __restrict__ w_rot,
    const int* __restrict__ batch, const int* __restrict__ chain,
    const float* __restrict__ w0, const float* __restrict__ w1,
    const float* __restrict__ w2, const float* __restrict__ w3,
    const float* __restrict__ w4, const float* __restrict__ w5,
    const float* __restrict__ w6, const float* __restrict__ w7,
    const float* __restrict__ w8, const float* __restrict__ w9,
    const float* __restrict__ w10,
    ushort* __restrict__ localb, ushort* __restrict__ pf, ushort* __restrict__ wt,
    float* __restrict__ b2b, float* __restrict__ rcnt) {
    __shared__ ushort tile[32][33];
    int bid = blockIdx.x, tid = threadIdx.x;
    if (bid < 2048) {
        size_t i4 = ((size_t)bid * 256 + tid) * 4;
        float4 v = *(const float4*)&local[i4];
        *(uint2*)&localb[i4] = make_uint2(pk2(v.x, v.y), pk2(v.z, v.w));
    } else if (bid < 2076) {
        int u = (bid - 2048) * 256 + tid;
        uint* pfu = (uint*)pf;
        if (u < 4096) {
            int fs = u >> 8, rem = u & 255, lane = rem >> 2, jj = rem & 3;
            int hi = lane >> 4, lo = lane & 15;
            int f = fs >> 1, s = fs & 1;
            int k0 = 32 * s + hi * 8 + 2 * jj;
            int c = 16 * f + lo;
            pfu[u] = pk2(w_p1[k0 * 128 + c], w_p1[(k0 + 1) * 128 + c]);
        } else if (u < 5120) {
            int u2 = u - 4096;
            int s2 = u2 >> 8, rem = u2 & 255, lane = rem >> 2, jj = rem & 3;
            int hi = lane >> 4, lo = lane & 15;
            int c0 = 32 * s2 + 8 * hi + 2 * jj;
            float v0 = 0.f, v1 = 0.f;
            if (lo < 8) {
                for (int q = 0; q < 64; q++) {
                    float wbq = wb[q * 8 + lo];
                    v0 += w_p2[c0 * 64 + q] * wbq;
                    v1 += w_p2[(c0 + 1) * 64 + q] * wbq;
                }
            }
            pfu[u] = pk2(v0, v1);
        } else if (u < 7168) {
            int u2 = u - 5120;
            int fs = u2 >> 8, rem = u2 & 255, lane = rem >> 2, jj = rem & 3;
            int hi = lane >> 4, lo = lane & 15;
            int f = fs >> 1, s = fs & 1;
            int k0 = 32 * s + hi * 8 + 2 * jj;
            int c = 16 * f + lo;
            float v0 = (k0 < 16) ? w_dist[k0 * 64 + c] : (k0 < 31) ? w_dir[(k0 - 16) * 64 + c]
                     : (k0 < 43) ? w_rot[(k0 - 31) * 64 + c] : 0.f;
            int k1 = k0 + 1;
            float v1 = (k1 < 16) ? w_dist[k1 * 64 + c] : (k1 < 31) ? w_dir[(k1 - 16) * 64 + c]
                     : (k1 < 43) ? w_rot[(k1 - 31) * 64 + c] : 0.f;
            pfu[u] = pk2(v0, v1);
        }
    } else if (bid < 3404) {
        int fb = bid - 2076;
        const int zbase[12] = {0, 128, 256, 384, 512, 576, 640, 704, 1008, 1136, 1200, 1328};
        int z = 0;
        #pragma unroll
        for (int i = 0; i < 11; i++) if (fb >= zbase[i + 1]) z = i + 1;
        int loc = fb - zbase[z];
        const float* W; int K, N; size_t off;
        switch (z) {
            case 0:  W = w0;  K = 256; N = 512; off = 0;       break;
            case 1:  W = w1;  K = 256; N = 512; off = 131072;  break;
            case 2:  W = w2;  K = 256; N = 512; off = 262144;  break;
            case 3:  W = w3;  K = 256; N = 512; off = 393216;  break;
            case 4:  W = w4;  K = 256; N = 256; off = 524288;  break;
            case 5:  W = w5;  K = 256; N = 256; off = 589824;  break;
            case 6:  W = w6;  K = 256; N = 256; off = 655360;  break;
            case 7:  W = w7;  K = 608; N = 512; off = 720896;  break;
            case 8:  W = w8;  K = 512; N = 256; off = 1032192; break;
            case 9:  W = w9;  K = 256; N = 256; off = 1163264; break;
            default: W = w10; K = 512; N = 256; off = 1228800; break;
        }
        int nx = N >> 5;
        int bn = (loc % nx) * 32, bk = (loc / nx) * 32;
        int tx = tid & 31, ty = tid >> 5;
        #pragma unroll
        for (int i = 0; i < 32; i += 8)
            tile[ty + i][tx] = f2bf(W[(size_t)(bk + ty + i) * N + bn + tx]);
        __syncthreads();
        #pragma unroll
        for (int i = 0; i < 32; i += 8)
            wt[off + (size_t)(bn + ty + i) * K + bk + tx] = tile[tx][ty + i];
    } else {
        if (tid < 8) {
            float s = 0.f;
            for (int q = 0; q < 64; q++) s += b_p2[q] * wb[q * 8 + tid];
            b2b[tid] = s;
        } else if (tid < 40) {
            int seg = tid - 8;
            int lo = lower_bound_i(batch, NN, seg);
            int hi = lower_bound_i(batch, NN, seg + 1);
            rcnt[seg] = 1.f / fmaxf((float)(hi - lo), 1.f);
        } else if (tid < 104) {
            int seg = tid - 40;
            int lo = lower_bound_i(chain, NN, seg);
            int hi = lower_bound_i(chain, NN, seg + 1);
            rcnt[32 + seg] = 1.f / fmaxf((float)(hi - lo), 1.f);
        }
    }
}

// ---------------- raw pair features (inline frames) ----------------
__global__ __launch_bounds__(256) void pair_raw_kernel(
    const float* __restrict__ pos, const int* __restrict__ nbr,
    const int* __restrict__ resi, const int* __restrict__ chain,
    ushort* __restrict__ feat, int* __restrict__ relidx, ushort* __restrict__ tfb) {
    int p = blockIdx.x * 256 + threadIdx.x;
    int n = p >> 5, k = p & 31;
    int j = nbr[p];
    int same = (chain[j] == chain[n]);
    int off = min(max(resi[j] - resi[n], -32), 32) + 32;
    relidx[p] = same ? off : -1;

    float can0 = pos[n * 15 + 3], can1 = pos[n * 15 + 4], can2 = pos[n * 15 + 5];
    float cbn0 = pos[n * 15 + 12], cbn1 = pos[n * 15 + 13], cbn2 = pos[n * 15 + 14];
    float Rn[9], Rj[9];
    frames_of(pos + (size_t)n * 15, Rn);
    float pj[15];
    #pragma unroll
    for (int i = 0; i < 15; i++) pj[i] = pos[j * 15 + i];
    frames_of(pj, Rj);

    float fe[43];
    float d0 = pj[12] - cbn0, d1 = pj[13] - cbn1, d2 = pj[14] - cbn2;
    float dcb = sqrtf(d0 * d0 + d1 * d1 + d2 * d2 + 1e-8f);
    #pragma unroll
    for (int i = 0; i < 16; i++) {
        float c = (22.f / 15.f) * (float)i;
        float z = (dcb - c) * (1.f / 1.375f);
        fe[i] = __expf(-z * z);
    }
    #pragma unroll
    for (int a = 0; a < 5; a++) {
        float vx = pj[a * 3 + 0] - can0;
        float vy = pj[a * 3 + 1] - can1;
        float vz = pj[a * 3 + 2] - can2;
        float invv = rsqrtf(vx * vx + vy * vy + vz * vz + 1e-8f);
        fe[16 + a * 3 + 0] = vx * invv;
        fe[16 + a * 3 + 1] = vy * invv;
        fe[16 + a * 3 + 2] = vz * invv;
    }
    #pragma unroll
    for (int b = 0; b < 3; b++)
        #pragma unroll
        for (int c2 = 0; c2 < 3; c2++)
            fe[31 + b * 3 + c2] = Rn[0 + b] * Rj[0 + c2] + Rn[3 + b] * Rj[3 + c2] + Rn[6 + b] * Rj[6 + c2];
    float t0 = pj[3] - can0, t1 = pj[4] - can1, t2 = pj[5] - can2;
    #pragma unroll
    for (int b = 0; b < 3; b++)
        fe[40 + b] = Rn[0 + b] * t0 + Rn[3 + b] * t1 + Rn[6 + b] * t2;

    #pragma unroll
    for (int q = 0; q < 8; q++) {
        uint4 w;
        float v0 = (q * 8 + 0 < 43) ? fe[q * 8 + 0] : 0.f;
        float v1 = (q * 8 + 1 < 43) ? fe[q * 8 + 1] : 0.f;
        float v2 = (q * 8 + 2 < 43) ? fe[q * 8 + 2] : 0.f;
        float v3 = (q * 8 + 3 < 43) ? fe[q * 8 + 3] : 0.f;
        float v4 = (q * 8 + 4 < 43) ? fe[q * 8 + 4] : 0.f;
        float v5 = (q * 8 + 5 < 43) ? fe[q * 8 + 5] : 0.f;
        float v6 = (q * 8 + 6 < 43) ? fe[q * 8 + 6] : 0.f;
        float v7 = (q * 8 + 7 < 43) ? fe[q * 8 + 7] : 0.f;
        w.x = pk2(v0, v1); w.y = pk2(v2, v3); w.z = pk2(v4, v5); w.w = pk2(v6, v7);
        *(uint4*)&feat[(size_t)p * 64 + q * 8] = w;
    }
    float rt0 = fe[40], rt1 = fe[41], rt2 = fe[42];
    float dr2 = rt0 * rt0 + rt1 * rt1 + rt2 * rt2 + 1e-8f;
    float invdr = rsqrtf(dr2);
    float drel = dr2 * invdr;
    ushort* tf = tfb + (size_t)n * 608 + k * 19;
    #pragma unroll
    for (int i = 0; i < 16; i++) {
        float c = (22.f / 15.f) * (float)i;
        float z = (drel - c) * (1.f / 1.375f);
        tf[i] = f2bf(__expf(-z * z));
    }
    tf[16] = f2bf(rt0 * invdr);
    tf[17] = f2bf(rt1 * invdr);
    tf[18] = f2bf(rt2 * invdr);
}

// ---------------- pair stage0: feat-proj MFMA + relpos + LN, in-place ----------------
__global__ __launch_bounds__(256) void pair_pre_kernel(
    ushort* feat, const int* __restrict__ relidx,
    const float* __restrict__ w_relpos, const ushort* __restrict__ pf,
    const float* __restrict__ lng, const float* __restrict__ lnb) {
    int tid = threadIdx.x;
    int wid = tid >> 6, lane = tid & 63, hi = lane >> 4, lo = lane & 15;
    bf16x8 wf[8];
    #pragma unroll
    for (int fs = 0; fs < 8; fs++) wf[fs] = *(const bf16x8*)&pf[10240 + fs * 512 + lane * 8];
    float sg_r[4][4], sbt_r[4][4];
    #pragma unroll
    for (int f = 0; f < 4; f++)
        #pragma unroll
        for (int r = 0; r < 4; r++) {
            int c = 16 * f + 4 * hi + r;
            sg_r[f][r] = lng[c];
            sbt_r[f][r] = lnb[c];
        }
    const f32x4 zz = {0.f, 0.f, 0.f, 0.f};
    for (int t = blockIdx.x * 4 + wid; t < (NN * KK / 16); t += 16384) {
        int r0 = t << 4;
        bf16x8 bp0 = *(const bf16x8*)(feat + (size_t)(r0 + lo) * 64 + hi * 8);
        bf16x8 bp1 = *(const bf16x8*)(feat + (size_t)(r0 + lo) * 64 + 32 + hi * 8);
        f32x4 a0f[4];
        #pragma unroll
        for (int f = 0; f < 4; f++) {
            a0f[f] = __builtin_amdgcn_mfma_f32_16x16x32_bf16(wf[f * 2 + 0], bp0, zz, 0, 0, 0);
            a0f[f] = __builtin_amdgcn_mfma_f32_16x16x32_bf16(wf[f * 2 + 1], bp1, a0f[f], 0, 0, 0);
        }
        int ridx = relidx[r0 + lo];
        float val[4][4];
        float part = 0.f;
        #pragma unroll
        for (int f = 0; f < 4; f++)
            #pragma unroll
            for (int r = 0; r < 4; r++) {
                int c = 16 * f + 4 * hi + r;
                float rv = (ridx >= 0) ? w_relpos[ridx * 64 + c] : 0.f;
                float v = a0f[f][r] + rv;
                val[f][r] = v;
                part += v;
            }
        part += __shfl_xor(part, 16);
        part += __shfl_xor(part, 32);
        float mean = part * (1.f / 64.f);
        float v2 = 0.f;
        #pragma unroll
        for (int f = 0; f < 4; f++)
            #pragma unroll
            for (int r = 0; r < 4; r++) {
                float dv = val[f][r] - mean;
                val[f][r] = dv;
                v2 += dv * dv;
            }
        v2 += __shfl_xor(v2, 16);
        v2 += __shfl_xor(v2, 32);
        float rs = rsqrtf(v2 * (1.f / 64.f) + 1e-5f);
        #pragma unroll
        for (int f = 0; f < 4; f++) {
            float v0 = val[f][0] * rs * sg_r[f][0] + sbt_r[f][0];
            float v1 = val[f][1] * rs * sg_r[f][1] + sbt_r[f][1];
            float v2b = val[f][2] * rs * sg_r[f][2] + sbt_r[f][2];
            float v3 = val[f][3] * rs * sg_r[f][3] + sbt_r[f][3];
            *(uint2*)(feat + (size_t)(r0 + lo) * 64 + 16 * f + 4 * hi) =
                make_uint2(pk2(v0, v1), pk2(v2b, v3));
        }
    }
}

// ---------------- pair MLP: pln -> 128 gelu -> @W2B -> bias ----------------
__global__ __launch_bounds__(256) void pair_mlp2_kernel(
    const ushort* __restrict__ pln, const ushort* __restrict__ pf,
    const float* __restrict__ b_p1, const float* __restrict__ b2b,
    float* __restrict__ bias) {
    __shared__ __align__(16) ushort hx[4 * 2048];
    int tid = threadIdx.x;
    int wid = tid >> 6, lane = tid & 63, hi = lane >> 4, lo = lane & 15;
    bf16x8 w1f[16];
    #pragma unroll
    for (int fs = 0; fs < 16; fs++) w1f[fs] = *(const bf16x8*)&pf[fs * 512 + lane * 8];
    bf16x8 w2f[4];
    #pragma unroll
    for (int s2 = 0; s2 < 4; s2++) w2f[s2] = *(const bf16x8*)&pf[8192 + s2 * 512 + lane * 8];
    float b2b_r[4];
    #pragma unroll
    for (int r = 0; r < 4; r++) b2b_r[r] = (hi < 2) ? b2b[4 * hi + r] : 0.f;
    float sb1_r[8][4];
    #pragma unroll
    for (int f = 0; f < 8; f++)
        #pragma unroll
        for (int r = 0; r < 4; r++) sb1_r[f][r] = b_p1[16 * f + 4 * hi + r];

    ushort* hxw = &hx[wid * 2048];
    const f32x4 zz = {0.f, 0.f, 0.f, 0.f};
    for (int t = blockIdx.x * 4 + wid; t < (NN * KK / 16); t += 16384) {
        int r0 = t << 4;
        bf16x8 bh0 = *(const bf16x8*)(pln + (size_t)(r0 + lo) * 64 + hi * 8);
        bf16x8 bh1 = *(const bf16x8*)(pln + (size_t)(r0 + lo) * 64 + 32 + hi * 8);
        #pragma unroll
        for (int f = 0; f < 8; f++) {
            f32x4 acch = __builtin_amdgcn_mfma_f32_16x16x32_bf16(w1f[f * 2 + 0], bh0, zz, 0, 0, 0);
            acch = __builtin_amdgcn_mfma_f32_16x16x32_bf16(w1f[f * 2 + 1], bh1, acch, 0, 0, 0);
            int c0 = 16 * f + 4 * hi;
            float v0 = gelu_f(acch[0] + sb1_r[f][0]);
            float v1 = gelu_f(acch[1] + sb1_r[f][1]);
            float v2b = gelu_f(acch[2] + sb1_r[f][2]);
            float v3 = gelu_f(acch[3] + sb1_r[f][3]);
            int idx = (lo * 128 + c0) ^ ((lo & 7) << 3);
            *(uint2*)&hxw[idx] = make_uint2(pk2(v0, v1), pk2(v2b, v3));
        }
        f32x4 acc = zz;
        #pragma unroll
        for (int s2 = 0; s2 < 4; s2++) {
            int idx = (lo * 128 + 32 * s2 + 8 * hi) ^ ((lo & 7) << 3);
            bf16x8 bh = *(const bf16x8*)&hxw[idx];
            acc = __builtin_amdgcn_mfma_f32_16x16x32_bf16(w2f[s2], bh, acc, 0, 0, 0);
        }
        if (hi < 2) {
            int n = r0 >> 5, kb = (r0 & 31) + lo;
            #pragma unroll
            for (int r = 0; r < 4; r++)
                bias[(size_t)n * 256 + (4 * hi + r) * 32 + kb] = acc[r] + b2b_r[r];
        }
    }
}

// ---------------- GEMM core T (BM=128, BN=128) ----------------
__device__ __forceinline__ void gemm_coreT(
    const ushort* __restrict__ A, const ushort* __restrict__ Wt,
    int K, int row0, int colW0, int tid,
    ushort* sA, ushort* sB, f32x4 acc[4][4]) {
    int wid = tid >> 6, lane = tid & 63, lo = lane & 15, hi = lane >> 4;
    int wr = wid >> 1, wc = wid & 1;
    int ar = tid >> 1, akh = (tid & 1) * 16;
    for (int kt = 0; kt < K; kt += 32) {
        const ushort* ap = &A[(size_t)(row0 + ar) * K + kt + akh];
        uint4 a01 = *(const uint4*)ap;
        uint4 a23 = *(const uint4*)(ap + 8);
        const ushort* bp = &Wt[(size_t)(colW0 + ar) * K + kt + akh];
        uint4 b01 = *(const uint4*)bp;
        uint4 b23 = *(const uint4*)(bp + 8);
        __syncthreads();
        *(uint4*)&sA[ar * 40 + akh] = a01;
        *(uint4*)&sA[ar * 40 + akh + 8] = a23;
        *(uint4*)&sB[ar * 40 + akh] = b01;
        *(uint4*)&sB[ar * 40 + akh + 8] = b23;
        __syncthreads();
        bf16x8 af[4], bfr[4];
        #pragma unroll
        for (int mi = 0; mi < 4; mi++) af[mi] = *(const bf16x8*)&sA[(wr * 64 + mi * 16 + lo) * 40 + hi * 8];
        #pragma unroll
        for (int ni = 0; ni < 4; ni++) bfr[ni] = *(const bf16x8*)&sB[(wc * 64 + ni * 16 + lo) * 40 + hi * 8];
        #pragma unroll
        for (int mi = 0; mi < 4; mi++)
            #pragma unroll
            for (int ni = 0; ni < 4; ni++)
                acc[mi][ni] = __builtin_amdgcn_mfma_f32_16x16x32_bf16(af[mi], bfr[ni], acc[mi][ni], 0, 0, 0);
    }
}

// ---------------- t1 GEMM ----------------
__global__ __launch_bounds__(256) void gemm_t1T(
    const ushort* __restrict__ A, const ushort* __restrict__ Wt, ushort* __restrict__ C,
    int K, int Nc) {
    __shared__ __align__(16) ushort sA[128 * 40];
    __shared__ __align__(16) ushort sB[128 * 40];
    int row0 = blockIdx.y * 128, col0 = blockIdx.x * 128;
    int tid = threadIdx.x;
    const f32x4 zz = {0.f, 0.f, 0.f, 0.f};
    f32x4 acc[4][4] = {{zz, zz, zz, zz}, {zz, zz, zz, zz}, {zz, zz, zz, zz}, {zz, zz, zz, zz}};
    gemm_coreT(A, Wt, K, row0, col0, tid, sA, sB, acc);
    int wid = tid >> 6, lane = tid & 63, lo = lane & 15, hi = lane >> 4;
    int wr = wid >> 1, wc = wid & 1;
    #pragma unroll
    for (int ni = 0; ni < 4; ni++) {
        int col = col0 + wc * 64 + ni * 16 + lo;
        #pragma unroll
        for (int mi = 0; mi < 4; mi++) {
            #pragma unroll
            for (int r = 0; r < 4; r++) {
                int row = row0 + wr * 64 + mi * 16 + hi * 4 + r;
                C[(size_t)row * Nc + col] = f2bf(gelu_f(acc[mi][ni][r]));
            }
        }
    }
}

// ---------------- small-tile GEMM (BM=64, BN=64) ----------------
__global__ __launch_bounds__(256) void gemm_n64s(
    const ushort* __restrict__ A, const ushort* __restrict__ Wt, float* __restrict__ C,
    int K, int Nc, const float* __restrict__ bias, const float* __restrict__ addp) {
    __shared__ __align__(16) ushort sA[64 * 40];
    __shared__ __align__(16) ushort sB[64 * 40];
    int row0 = blockIdx.y * 64, col0 = blockIdx.x * 64;
    int tid = threadIdx.x;
    int wid = tid >> 6, lane = tid & 63, lo = lane & 15, hi = lane >> 4;
    int wr = wid >> 1, wc = wid & 1;
    int ar = tid >> 2, akh = (tid & 3) * 8;
    const f32x4 zz = {0.f, 0.f, 0.f, 0.f};
    f32x4 acc[2][2] = {{zz, zz}, {zz, zz}};
    for (int kt = 0; kt < K; kt += 32) {
        uint4 a0 = *(const uint4*)&A[(size_t)(row0 + ar) * K + kt + akh];
        uint4 b0 = *(const uint4*)&Wt[(size_t)(col0 + ar) * K + kt + akh];
        __syncthreads();
        *(uint4*)&sA[ar * 40 + akh] = a0;
        *(uint4*)&sB[ar * 40 + akh] = b0;
        __syncthreads();
        bf16x8 af[2], bfr[2];
        #pragma unroll
        for (int mi = 0; mi < 2; mi++) af[mi] = *(const bf16x8*)&sA[(wr * 32 + mi * 16 + lo) * 40 + hi * 8];
        #pragma unroll
        for (int ni = 0; ni < 2; ni++) bfr[ni] = *(const bf16x8*)&sB[(wc * 32 + ni * 16 + lo) * 40 + hi * 8];
        #pragma unroll
        for (int mi = 0; mi < 2; mi++)
            #pragma unroll
            for (int ni = 0; ni < 2; ni++)
                acc[mi][ni] = __builtin_amdgcn_mfma_f32_16x16x32_bf16(af[mi], bfr[ni], acc[mi][ni], 0, 0, 0);
    }
    #pragma unroll
    for (int ni = 0; ni < 2; ni++) {
        int col = col0 + wc * 32 + ni * 16 + lo;
        float bc = bias ? bias[col] : 0.f;
        #pragma unroll
        for (int mi = 0; mi < 2; mi++) {
            #pragma unroll
            for (int r = 0; r < 4; r++) {
                int row = row0 + wr * 32 + mi * 16 + hi * 4 + r;
                float v = acc[mi][ni][r] + bc;
                if (addp) v += addp[(size_t)row * Nc + col];
                C[(size_t)row * Nc + col] = v;
            }
        }
    }
}

// ---------------- fused QKV GEMM T ----------------
__global__ __launch_bounds__(256) void gemm_qkvT(
    const ushort* __restrict__ A, const ushort* __restrict__ Wt3,
    float* __restrict__ qb, ushort* __restrict__ kb, ushort* __restrict__ vb) {
    __shared__ __align__(16) ushort sA[128 * 40];
    __shared__ __align__(16) ushort sB[128 * 40];
    int row0 = blockIdx.y * 128, col0 = blockIdx.x * 128;
    int wsel = col0 >> 8, colW = col0 & 255;
    int tid = threadIdx.x;
    const f32x4 zz = {0.f, 0.f, 0.f, 0.f};
    f32x4 acc[4][4] = {{zz, zz, zz, zz}, {zz, zz, zz, zz}, {zz, zz, zz, zz}, {zz, zz, zz, zz}};
    gemm_coreT(A, Wt3, 256, row0, col0, tid, sA, sB, acc);
    int wid = tid >> 6, lane = tid & 63, lo = lane & 15, hi = lane >> 4;
    int wr = wid >> 1, wc = wid & 1;
    #pragma unroll
    for (int ni = 0; ni < 4; ni++) {
        int colo = colW + wc * 64 + ni * 16 + lo;
        #pragma unroll
        for (int mi = 0; mi < 4; mi++) {
            #pragma unroll
            for (int r = 0; r < 4; r++) {
                int row = row0 + wr * 64 + mi * 16 + hi * 4 + r;
                float v = acc[mi][ni][r];
                if (wsel == 0) qb[(size_t)row * 256 + colo] = v;
                else if (wsel == 1) kb[(size_t)row * 256 + colo] = f2bf(v);
                else vb[(size_t)row * 256 + colo] = f2bf(v);
            }
        }
    }
}

// ---------------- fused FFN GEMM T ----------------
__global__ __launch_bounds__(256) void gemm_ffnT(
    const ushort* __restrict__ A, const ushort* __restrict__ Wt4,
    ushort* __restrict__ o0, ushort* __restrict__ o1,
    ushort* __restrict__ o2, ushort* __restrict__ o3) {
    __shared__ __align__(16) ushort sA[128 * 40];
    __shared__ __align__(16) ushort sB[128 * 40];
    int row0 = blockIdx.y * 128, col0 = blockIdx.x * 128;
    int wsel = col0 >> 9, colW = col0 & 511;
    ushort* O = (wsel == 0) ? o0 : (wsel == 1) ? o1 : (wsel == 2) ? o2 : o3;
    int tid = threadIdx.x;
    const f32x4 zz = {0.f, 0.f, 0.f, 0.f};
    f32x4 acc[4][4] = {{zz, zz, zz, zz}, {zz, zz, zz, zz}, {zz, zz, zz, zz}, {zz, zz, zz, zz}};
    gemm_coreT(A, Wt4, 256, row0, col0, tid, sA, sB, acc);
    int wid = tid >> 6, lane = tid & 63, lo = lane & 15, hi = lane >> 4;
    int wr = wid >> 1, wc = wid & 1;
    #pragma unroll
    for (int ni = 0; ni < 4; ni++) {
        int colo = colW + wc * 64 + ni * 16 + lo;
        #pragma unroll
        for (int mi = 0; mi < 4; mi++) {
            #pragma unroll
            for (int r = 0; r < 4; r++) {
                int row = row0 + wr * 64 + mi * 16 + hi * 4 + r;
                float v = acc[mi][ni][r];
                if (wsel > 0) v = gelu_f(v);
                O[(size_t)row * 512 + colo] = f2bf(v);
            }
        }
    }
}

// ---------------- attention ----------------
__global__ __launch_bounds__(256) void attn_kernel(
    const float* __restrict__ q, const ushort* __restrict__ kp, const ushort* __restrict__ vp,
    const float* __restrict__ bias, const int* __restrict__ nbr, ushort* __restrict__ o) {
    int n = blockIdx.x;
    __shared__ float qs[256];
    __shared__ int js[32];
    __shared__ float ls[256];
    __shared__ __align__(16) uint4 vs[32 * 33];
    int t = threadIdx.x;
    qs[t] = q[(size_t)n * 256 + t];
    if (t < 32) js[t] = nbr[n * 32 + t];
    __syncthreads();
    int vrow = t >> 3, vseg = t & 7;
    const uint4* vsrc = (const uint4*)(vp + (size_t)js[vrow] * 256);
    uint4 vr0 = vsrc[vseg * 4 + 0];
    uint4 vr1 = vsrc[vseg * 4 + 1];
    uint4 vr2 = vsrc[vseg * 4 + 2];
    uint4 vr3 = vsrc[vseg * 4 + 3];
    int h = t >> 5, k = t & 31;
    int j = js[k];
    const bf16x8* kr = (const bf16x8*)(kp + (size_t)j * 256 + h * 32);
    bf16x8 kv0 = kr[0], kv1 = kr[1], kv2 = kr[2], kv3 = kr[3];
    const float* qh = qs + h * 32;
    float dot = 0.f;
    #pragma unroll
    for (int i = 0; i < 8; i++) dot += qh[i] * bf2f((ushort)kv0[i]);
    #pragma unroll
    for (int i = 0; i < 8; i++) dot += qh[8 + i] * bf2f((ushort)kv1[i]);
    #pragma unroll
    for (int i = 0; i < 8; i++) dot += qh[16 + i] * bf2f((ushort)kv2[i]);
    #pragma unroll
    for (int i = 0; i < 8; i++) dot += qh[24 + i] * bf2f((ushort)kv3[i]);
    float l = dot * 0.17677669529663687f + bias[(size_t)n * 256 + t];
    float mx = l;
    #pragma unroll
    for (int m = 16; m > 0; m >>= 1) mx = fmaxf(mx, __shfl_xor(mx, m));
    float e = __expf(l - mx);
    float sum = e;
    #pragma unroll
    for (int m = 16; m > 0; m >>= 1) sum += __shfl_xor(sum, m);
    ls[t] = e / sum;
    vs[vrow * 33 + vseg * 4 + 0] = vr0;
    vs[vrow * 33 + vseg * 4 + 1] = vr1;
    vs[vrow * 33 + vseg * 4 + 2] = vr2;
    vs[vrow * 33 + vseg * 4 + 3] = vr3;
    __syncthreads();
    const ushort* vsu = (const ushort*)vs;
    const float* lh = ls + h * 32;
    float acc = 0.f;
    #pragma unroll
    for (int kk = 0; kk < 32; kk++)
        acc += lh[kk] * bf2f(vsu[kk * 264 + h * 32 + k]);
    o[(size_t)n * 256 + t] = f2bf(acc);
}

// ---------------- LN(a+b) ----------------
__global__ __launch_bounds__(256) void ln_add_kernel(
    const float* __restrict__ a, const float* __restrict__ b,
    const float* __restrict__ g, const float* __restrict__ be,
    float* __restrict__ xout, ushort* __restrict__ xbout, float* __restrict__ sout) {
    int row = blockIdx.x * 4 + (threadIdx.x >> 6);
    int lane = threadIdx.x & 63;
    size_t base = (size_t)row * 256 + lane * 4;
    float4 av = *(const float4*)(a + base);
    float4 bv = *(const float4*)(b + base);
    float s0 = av.x + bv.x, s1 = av.y + bv.y, s2 = av.z + bv.z, s3 = av.w + bv.w;
    float sum = wave_sum64(s0 + s1 + s2 + s3);
    float mean = sum * (1.f / 256.f);
    float d0 = s0 - mean, d1 = s1 - mean, d2 = s2 - mean, d3 = s3 - mean;
    float v = wave_sum64(d0 * d0 + d1 * d1 + d2 * d2 + d3 * d3);
    float rs = rsqrtf(v * (1.f / 256.f) + 1e-5f);
    float4 gv = *(const float4*)(g + lane * 4);
    float4 bev = *(const float4*)(be + lane * 4);
    float4 xo;
    xo.x = d0 * rs * gv.x + bev.x;
    xo.y = d1 * rs * gv.y + bev.y;
    xo.z = d2 * rs * gv.z + bev.z;
    xo.w = d3 * rs * gv.w + bev.w;
    *(float4*)(xout + base) = xo;
    *(uint2*)(xbout + base) = make_uint2(pk2(xo.x, xo.y), pk2(xo.z, xo.w));
    float4 so; so.x = s0; so.y = s1; so.z = s2; so.w = s3;
    *(float4*)(sout + base) = so;
}

// ---------------- segment partial sums ----------------
__global__ __launch_bounds__(256) void seg_partial_kernel(
    const ushort* __restrict__ up, const int* __restrict__ batch, const int* __restrict__ chain,
    float* __restrict__ mb_acc, float* __restrict__ mc_acc) {
    int r0 = blockIdx.x * 32;
    int t = threadIdx.x;
    float ab0 = 0.f, ab1 = 0.f, ac0 = 0.f, ac1 = 0.f;
    int curb = batch[r0], curc = chain[r0];
    for (int r = r0; r < r0 + 32; r++) {
        int b = batch[r], c = chain[r];
        if (b != curb) {
            atomicAdd(&mb_acc[curb * 512 + t], ab0);
            atomicAdd(&mb_acc[curb * 512 + 256 + t], ab1);
            ab0 = ab1 = 0.f; curb = b;
        }
        if (c != curc) {
            atomicAdd(&mc_acc[curc * 512 + t], ac0);
            atomicAdd(&mc_acc[curc * 512 + 256 + t], ac1);
            ac0 = ac1 = 0.f; curc = c;
        }
        float v0 = bf2f(up[(size_t)r * 512 + t]);
        float v1 = bf2f(up[(size_t)r * 512 + 256 + t]);
        ab0 += v0; ab1 += v1; ac0 += v0; ac1 += v1;
    }
    atomicAdd(&mb_acc[curb * 512 + t], ab0);
    atomicAdd(&mb_acc[curb * 512 + 256 + t], ab1);
    atomicAdd(&mc_acc[curc * 512 + t], ac0);
    atomicAdd(&mc_acc[curc * 512 + 256 + t], ac1);
}

// ---------------- hidden combine (raw sums * rcnt) ----------------
__global__ __launch_bounds__(256) void hidden_kernel(
    const ushort* __restrict__ up, const ushort* __restrict__ cg, const ushort* __restrict__ bg,
    ushort* __restrict__ lg, const float* __restrict__ mb, const float* __restrict__ mc,
    const int* __restrict__ batch, const int* __restrict__ chain,
    const float* __restrict__ rcnt) {
    size_t e4 = ((size_t)blockIdx.x * 256 + threadIdx.x) * 4;
    int n = (int)(e4 >> 9), d = (int)(e4 & 511);
    float rb = rcnt[batch[n]];
    float rc = rcnt[32 + chain[n]];
    float4 mbv = *(const float4*)&mb[batch[n] * 512 + d];
    float4 mcv = *(const float4*)&mc[chain[n] * 512 + d];
    uint2 u_up = *(const uint2*)&up[e4];
    uint2 u_cg = *(const uint2*)&cg[e4];
    uint2 u_bg = *(const uint2*)&bg[e4];
    uint2 u_lg = *(const uint2*)&lg[e4];
    float h0 = bf2f((ushort)u_bg.x) * (mbv.x * rb) + bf2f((ushort)u_cg.x) * (mcv.x * rc)
             + bf2f((ushort)u_lg.x) * bf2f((ushort)u_up.x);
    float h1 = bf2f((ushort)(u_bg.x >> 16)) * (mbv.y * rb) + bf2f((ushort)(u_cg.x >> 16)) * (mcv.y * rc)
             + bf2f((ushort)(u_lg.x >> 16)) * bf2f((ushort)(u_up.x >> 16));
    float h2 = bf2f((ushort)u_bg.y) * (mbv.z * rb) + bf2f((ushort)u_cg.y) * (mcv.z * rc)
             + bf2f((ushort)u_lg.y) * bf2f((ushort)u_up.y);
    float h3 = bf2f((ushort)(u_bg.y >> 16)) * (mbv.w * rb) + bf2f((ushort)(u_cg.y >> 16)) * (mcv.w * rc)
             + bf2f((ushort)(u_lg.y >> 16)) * bf2f((ushort)(u_up.y >> 16));
    *(uint2*)&lg[e4] = make_uint2(pk2(h0, h1), pk2(h2, h3));
}

// ---------------- final ----------------
__global__ __launch_bounds__(256) void final_kernel(
    const float* __restrict__ x1, const float* __restrict__ y2, const float* __restrict__ inc1,
    const float* __restrict__ ug, const float* __restrict__ ub,
    const float* __restrict__ fg, const float* __restrict__ fb, float* __restrict__ out) {
    int row = blockIdx.x * 4 + (threadIdx.x >> 6);
    int lane = threadIdx.x & 63;
    size_t base = (size_t)row * 256 + lane * 4;
    float4 xv = *(const float4*)(x1 + base);
    float4 yv = *(const float4*)(y2 + base);
    float4 iv = *(const float4*)(inc1 + base);
    float s0 = xv.x + yv.x, s1 = xv.y + yv.y, s2 = xv.z + yv.z, s3 = xv.w + yv.w;
    float t0 = iv.x + yv.x, t1 = iv.y + yv.y, t2 = iv.z + yv.z, t3 = iv.w + yv.w;
    float sums = wave_sum64(s0 + s1 + s2 + s3);
    float means = sums * (1.f / 256.f);
    float sd0 = s0 - means, sd1 = s1 - means, sd2 = s2 - means, sd3 = s3 - means;
    float vs = wave_sum64(sd0 * sd0 + sd1 * sd1 + sd2 * sd2 + sd3 * sd3);
    float rss = rsqrtf(vs * (1.f / 256.f) + 1e-5f);
    float sumt = wave_sum64(t0 + t1 + t2 + t3);
    float meant = sumt * (1.f / 256.f);
    float td0 = t0 - meant, td1 = t1 - meant, td2 = t2 - meant, td3 = t3 - meant;
    float vt = wave_sum64(td0 * td0 + td1 * td1 + td2 * td2 + td3 * td3);
    float rst = rsqrtf(vt * (1.f / 256.f) + 1e-5f);
    float4 ugv = *(const float4*)(ug + lane * 4);
    float4 ubv = *(const float4*)(ub + lane * 4);
    float4 fgv = *(const float4*)(fg + lane * 4);
    float4 fbv = *(const float4*)(fb + lane * 4);
    float4 ov;
    ov.x = (sd0 * rss * ugv.x + ubv.x) + (td0 * rst * fgv.x + fbv.x);
    ov.y = (sd1 * rss * ugv.y + ubv.y) + (td1 * rst * fgv.y + fbv.y);
    ov.z = (sd2 * rss * ugv.z + ubv.z) + (td2 * rst * fgv.z + fbv.z);
    ov.w = (sd3 * rss * ugv.w + ubv.w) + (td3 * rst * fgv.w + fbv.w);
    *(float4*)(out + base) = ov;
}

// ---------------- launch ----------------
extern "C" void kernel_launch(void* const* d_in, const int* in_sizes, int n_in,
                              void* d_out, int out_size, void* d_ws, size_t ws_size,
                              hipStream_t stream) {
    const float* local    = (const float*)d_in[0];
    const float* pos      = (const float*)d_in[1];
    const int*   nbr      = (const int*)d_in[2];
    const int*   resi     = (const int*)d_in[3];
    const int*   chain    = (const int*)d_in[4];
    const int*   batch    = (const int*)d_in[5];
    const float* w_relpos = (const float*)d_in[7];
    const float* w_dist   = (const float*)d_in[8];
    const float* w_dir    = (const float*)d_in[9];
    const float* w_rot    = (const float*)d_in[10];
    const float* ln_pair_g = (const float*)d_in[11];
    const float* ln_pair_b = (const float*)d_in[12];
    const float* w_p1     = (const float*)d_in[13];
    const float* b_p1     = (const float*)d_in[14];
    const float* w_p2     = (const float*)d_in[15];
    const float* b_p2     = (const float*)d_in[16];
    const float* wq       = (const float*)d_in[17];
    const float* wk       = (const float*)d_in[18];
    const float* wv       = (const float*)d_in[19];
    const float* wb       = (const float*)d_in[20];
    const float* wo       = (const float*)d_in[21];
    const float* ln_a_g   = (const float*)d_in[22];
    const float* ln_a_b   = (const float*)d_in[23];
    const float* w_t1     = (const float*)d_in[24];
    const float* w_t2     = (const float*)d_in[25];
    const float* w_up     = (const float*)d_in[26];
    const float* w_lg     = (const float*)d_in[27];
    const float* w_cg     = (const float*)d_in[28];
    const float* w_bg     = (const float*)d_in[29];
    const float* w_out    = (const float*)d_in[30];
    const float* b_out    = (const float*)d_in[31];
    const float* ln_u_g   = (const float*)d_in[32];
    const float* ln_u_b   = (const float*)d_in[33];
    const float* ln_f_g   = (const float*)d_in[34];
    const float* ln_f_b   = (const float*)d_in[35];

    float* ws = (float*)d_ws;
    float* biasb     = ws + 73728;         // -> 2170880
    float* tfeat_out = ws + 2170880;       // -> 4268032
    float* x1        = ws + 4268032;       // -> 6365184
    float* inc1      = ws + 6365184;       // -> 8462336
    ushort* featb    = (ushort*)(ws + 8462336);  // -> 16850944
    int* relidx      = (int*)(ws + 16850944);    // -> 17113088
    ushort* tfb      = (ushort*)(ws + 17113088); // -> 19603456
    ushort* wt       = (ushort*)(ws + 19603456); // -> 20283392
    ushort* x1b      = (ushort*)(ws + 20283392); // -> 21331968
    ushort* localb   = (ushort*)(ws + 21331968); // -> 22380544
    ushort* tmp512u  = (ushort*)(ws + 22380544); // -> 24477696
    float* y2        = ws + 22380544;      // over tmp512u after t2 consumed
    float* yb        = ws + 17113088;      // over tfb after t1 consumed
    float* qb        = ws + 8462336;       // phase 2 over featb (consumed)
    ushort* kbu      = (ushort*)(ws + 10559488);
    ushort* vbu      = (ushort*)(ws + 11608064);
    ushort* obu      = (ushort*)(ws + 12656640);
    ushort* upbu     = (ushort*)(ws + 8462336);  // phase 3
    ushort* lgbu     = (ushort*)(ws + 10559488);
    ushort* cgbu     = (ushort*)(ws + 12656640);
    ushort* bgbu     = (ushort*)(ws + 14753792);
    float* mb        = ws + 24477696;
    float* mc        = ws + 24494080;
    ushort* pfmt     = (ushort*)(ws + 24526848);
    float* b2b       = ws + 24535040;
    float* rcnt      = ws + 24535048;      // 96 floats

    prep_kernel<<<3405, 256, 0, stream>>>(local, w_p1, w_p2, b_p2, wb,
                                          w_dist, w_dir, w_rot, batch, chain,
                                          w_up, w_lg, w_cg, w_bg, wq, wk, wv,
                                          w_t1, w_t2, wo, w_out,
                                          localb, pfmt, wt, b2b, rcnt);
    pair_raw_kernel<<<NN * KK / 256, 256, 0, stream>>>(pos, nbr, resi, chain,
                                                       featb, relidx, tfb);
    pair_pre_kernel<<<4096, 256, 0, stream>>>(featb, relidx, w_relpos, pfmt,
                                              ln_pair_g, ln_pair_b);
    pair_mlp2_kernel<<<4096, 256, 0, stream>>>(featb, pfmt, b_p1, b2b, biasb);
    // tfeat MLP
    gemm_t1T<<<dim3(4, 64), 256, 0, stream>>>(tfb, wt + 720896, tmp512u, 608, 512);
    gemm_n64s<<<dim3(4, 128), 256, 0, stream>>>(tmp512u, wt + 1032192, tfeat_out, 512, 256,
                                                nullptr, nullptr);
    // qkv
    gemm_qkvT<<<dim3(6, 64), 256, 0, stream>>>(localb, wt + 524288, qb, kbu, vbu);
    attn_kernel<<<NN, 256, 0, stream>>>(qb, kbu, vbu, biasb, nbr, obu);
    gemm_n64s<<<dim3(4, 128), 256, 0, stream>>>(obu, wt + 1163264, yb, 256, 256,
                                                nullptr, nullptr);
    ln_add_kernel<<<NN / 4, 256, 0, stream>>>(local, yb, ln_a_g, ln_a_b, x1, x1b, inc1);
    // FFN
    gemm_ffnT<<<dim3(16, 64), 256, 0, stream>>>(x1b, wt, upbu, lgbu, cgbu, bgbu);
    (void)hipMemsetAsync(mb, 0, (NBATCH + NCHAIN) * 512 * sizeof(float), stream);
    seg_partial_kernel<<<NN / 32, 256, 0, stream>>>(upbu, batch, chain, mb, mc);
    hidden_kernel<<<NN * 512 / 1024, 256, 0, stream>>>(upbu, cgbu, bgbu, lgbu, mb, mc,
                                                       batch, chain, rcnt);
    gemm_n64s<<<dim3(4, 128), 256, 0, stream>>>(lgbu, wt + 1228800, y2, 512, 256,
                                                b_out, tfeat_out);
    final_kernel<<<NN / 4, 256, 0, stream>>>(x1, y2, inc1, ln_u_g, ln_u_b, ln_f_g, ln_f_b, (float*)d_out);
}

// Round 17
// 245.263 us; speedup vs baseline: 1.1313x; 1.0236x over previous
//
#include <hip/hip_runtime.h>
#include <math.h>

#define NN 8192
#define KK 32
#define DD 256
#define PP 64
#define HH 8
#define DHH 32
#define NBATCH 32
#define NCHAIN 64

typedef __attribute__((ext_vector_type(8))) short bf16x8;
typedef __attribute__((ext_vector_type(4))) float f32x4;

// ---------------- helpers ----------------
__device__ __forceinline__ float gelu_f(float x) {
    float x3 = x * x * x;
    float e = __expf(fmaf(x3, -0.07135481f, x * -1.59576912f));
    return __fdividef(x, 1.f + e);
}

__device__ __forceinline__ float wave_sum64(float v) {
    #pragma unroll
    for (int m = 32; m > 0; m >>= 1) v += __shfl_xor(v, m);
    return v;
}

__device__ __forceinline__ ushort f2bf(float x) {
    union { float f; unsigned int u; } v; v.f = x;
    unsigned int r = v.u + 0x7fffu + ((v.u >> 16) & 1u);
    return (ushort)(r >> 16);
}

__device__ __forceinline__ float bf2f(ushort u) {
    union { unsigned int u; float f; } v; v.u = ((unsigned int)u) << 16;
    return v.f;
}

__device__ __forceinline__ uint pk2(float a, float b) {
    return (uint)f2bf(a) | ((uint)f2bf(b) << 16);
}

__device__ __forceinline__ void frames_of(const float* __restrict__ p, float R[9]) {
    float nx = p[0], ny = p[1], nz = p[2];
    float cax = p[3], cay = p[4], caz = p[5];
    float cx = p[6], cy = p[7], cz = p[8];
    float e1x = cx - cax, e1y = cy - cay, e1z = cz - caz;
    float inv = rsqrtf(e1x * e1x + e1y * e1y + e1z * e1z + 1e-8f);
    e1x *= inv; e1y *= inv; e1z *= inv;
    float ux = nx - cax, uy = ny - cay, uz = nz - caz;
    float dt = ux * e1x + uy * e1y + uz * e1z;
    float e2x = ux - dt * e1x, e2y = uy - dt * e1y, e2z = uz - dt * e1z;
    inv = rsqrtf(e2x * e2x + e2y * e2y + e2z * e2z + 1e-8f);
    e2x *= inv; e2y *= inv; e2z *= inv;
    float e3x = e1y * e2z - e1z * e2y;
    float e3y = e1z * e2x - e1x * e2z;
    float e3z = e1x * e2y - e1y * e2x;
    R[0] = e1x; R[1] = e2x; R[2] = e3x;
    R[3] = e1y; R[4] = e2y; R[5] = e3y;
    R[6] = e1z; R[7] = e2z; R[8] = e3z;
}

__device__ __forceinline__ int lower_bound_i(const int* a, int n, int v) {
    int lo = 0, hi = n;
    while (lo < hi) { int mid = (lo + hi) >> 1; if (a[mid] < v) lo = mid + 1; else hi = mid; }
    return lo;
}

// ---------------- prep: localb + pair frags + Wt transposes + b2b + rcnt + zero mb ----------------
__global__ __launch_bounds__(256) void prep_kernel(
    const float* __restrict__ local,
    const float* __restrict__ w_p1, const float* __restrict__ w_p2,
    const float* __restrict__ b_p2, const float* __restrict__ wb,
    const float* __restrict__ w_dist, const float* __restrict__ w_dir,
    const float* __restrict__ w_rot,
    const int* __restrict__ batch, const int* __restrict__ chain,
    const float* __restrict__ w0, const float* __restrict__ w1,
    const float* __restrict__ w2, const float* __restrict__ w3,
    const float* __restrict__ w4, const float* __restrict__ w5,
    const float* __restrict__ w6, const float* __restrict__ w7,
    const float* __restrict__ w8, const float* __restrict__ w9,
    const float* __restrict__ w10,
    ushort* __restrict__ localb, ushort* __restrict__ pf, ushort* __restrict__ wt,
    float* __restrict__ b2b, float* __restrict__ rcnt, float* __restrict__ mbz) {
    __shared__ ushort tile[32][33];
    int bid = blockIdx.x, tid = threadIdx.x;
    if (bid < 2048) {
        size_t i4 = ((size_t)bid * 256 + tid) * 4;
        float4 v = *(const float4*)&local[i4];
        *(uint2*)&localb[i4] = make_uint2(pk2(v.x, v.y), pk2(v.z, v.w));
    } else if (bid < 2076) {
        int u = (bid - 2048) * 256 + tid;
        uint* pfu = (uint*)pf;
        if (u < 4096) {
            int fs = u >> 8, rem = u & 255, lane = rem >> 2, jj = rem & 3;
            int hi = lane >> 4, lo = lane & 15;
            int f = fs >> 1, s = fs & 1;
            int k0 = 32 * s + hi * 8 + 2 * jj;
            int c = 16 * f + lo;
            pfu[u] = pk2(w_p1[k0 * 128 + c], w_p1[(k0 + 1) * 128 + c]);
        } else if (u < 5120) {
            int u2 = u - 4096;
            int s2 = u2 >> 8, rem = u2 & 255, lane = rem >> 2, jj = rem & 3;
            int hi = lane >> 4, lo = lane & 15;
            int c0 = 32 * s2 + 8 * hi + 2 * jj;
            float v0 = 0.f, v1 = 0.f;
            if (lo < 8) {
                for (int q = 0; q < 64; q++) {
                    float wbq = wb[q * 8 + lo];
                    v0 += w_p2[c0 * 64 + q] * wbq;
                    v1 += w_p2[(c0 + 1) * 64 + q] * wbq;
                }
            }
            pfu[u] = pk2(v0, v1);
        } else if (u < 7168) {
            int u2 = u - 5120;
            int fs = u2 >> 8, rem = u2 & 255, lane = rem >> 2, jj = rem & 3;
            int hi = lane >> 4, lo = lane & 15;
            int f = fs >> 1, s = fs & 1;
            int k0 = 32 * s + hi * 8 + 2 * jj;
            int c = 16 * f + lo;
            float v0 = (k0 < 16) ? w_dist[k0 * 64 + c] : (k0 < 31) ? w_dir[(k0 - 16) * 64 + c]
                     : (k0 < 43) ? w_rot[(k0 - 31) * 64 + c] : 0.f;
            int k1 = k0 + 1;
            float v1 = (k1 < 16) ? w_dist[k1 * 64 + c] : (k1 < 31) ? w_dir[(k1 - 16) * 64 + c]
                     : (k1 < 43) ? w_rot[(k1 - 31) * 64 + c] : 0.f;
            pfu[u] = pk2(v0, v1);
        }
    } else if (bid < 3404) {
        int fb = bid - 2076;
        const int zbase[12] = {0, 128, 256, 384, 512, 576, 640, 704, 1008, 1136, 1200, 1328};
        int z = 0;
        #pragma unroll
        for (int i = 0; i < 11; i++) if (fb >= zbase[i + 1]) z = i + 1;
        int loc = fb - zbase[z];
        const float* W; int K, N; size_t off;
        switch (z) {
            case 0:  W = w0;  K = 256; N = 512; off = 0;       break;
            case 1:  W = w1;  K = 256; N = 512; off = 131072;  break;
            case 2:  W = w2;  K = 256; N = 512; off = 262144;  break;
            case 3:  W = w3;  K = 256; N = 512; off = 393216;  break;
            case 4:  W = w4;  K = 256; N = 256; off = 524288;  break;
            case 5:  W = w5;  K = 256; N = 256; off = 589824;  break;
            case 6:  W = w6;  K = 256; N = 256; off = 655360;  break;
            case 7:  W = w7;  K = 608; N = 512; off = 720896;  break;
            case 8:  W = w8;  K = 512; N = 256; off = 1032192; break;
            case 9:  W = w9;  K = 256; N = 256; off = 1163264; break;
            default: W = w10; K = 512; N = 256; off = 1228800; break;
        }
        int nx = N >> 5;
        int bn = (loc % nx) * 32, bk = (loc / nx) * 32;
        int tx = tid & 31, ty = tid >> 5;
        #pragma unroll
        for (int i = 0; i < 32; i += 8)
            tile[ty + i][tx] = f2bf(W[(size_t)(bk + ty + i) * N + bn + tx]);
        __syncthreads();
        #pragma unroll
        for (int i = 0; i < 32; i += 8)
            wt[off + (size_t)(bn + ty + i) * K + bk + tx] = tile[tx][ty + i];
    } else if (bid == 3404) {
        if (tid < 8) {
            float s = 0.f;
            for (int q = 0; q < 64; q++) s += b_p2[q] * wb[q * 8 + tid];
            b2b[tid] = s;
        } else if (tid < 40) {
            int seg = tid - 8;
            int lo = lower_bound_i(batch, NN, seg);
            int hi = lower_bound_i(batch, NN, seg + 1);
            rcnt[seg] = 1.f / fmaxf((float)(hi - lo), 1.f);
        } else if (tid < 104) {
            int seg = tid - 40;
            int lo = lower_bound_i(chain, NN, seg);
            int hi = lower_bound_i(chain, NN, seg + 1);
            rcnt[32 + seg] = 1.f / fmaxf((float)(hi - lo), 1.f);
        }
    } else {
        // zero mb/mc accumulators: 48 blocks x 1024 floats
        size_t i4 = ((size_t)(bid - 3405) * 256 + tid) * 4;
        *(float4*)&mbz[i4] = make_float4(0.f, 0.f, 0.f, 0.f);
    }
}

// ---------------- raw pair features (inline frames) ----------------
__global__ __launch_bounds__(256) void pair_raw_kernel(
    const float* __restrict__ pos, const int* __restrict__ nbr,
    const int* __restrict__ resi, const int* __restrict__ chain,
    ushort* __restrict__ feat, int* __restrict__ relidx, ushort* __restrict__ tfb) {
    int p = blockIdx.x * 256 + threadIdx.x;
    int n = p >> 5, k = p & 31;
    int j = nbr[p];
    int same = (chain[j] == chain[n]);
    int off = min(max(resi[j] - resi[n], -32), 32) + 32;
    relidx[p] = same ? off : -1;

    float can0 = pos[n * 15 + 3], can1 = pos[n * 15 + 4], can2 = pos[n * 15 + 5];
    float cbn0 = pos[n * 15 + 12], cbn1 = pos[n * 15 + 13], cbn2 = pos[n * 15 + 14];
    float Rn[9], Rj[9];
    frames_of(pos + (size_t)n * 15, Rn);
    float pj[15];
    #pragma unroll
    for (int i = 0; i < 15; i++) pj[i] = pos[j * 15 + i];
    frames_of(pj, Rj);

    float fe[43];
    float d0 = pj[12] - cbn0, d1 = pj[13] - cbn1, d2 = pj[14] - cbn2;
    float dcb = sqrtf(d0 * d0 + d1 * d1 + d2 * d2 + 1e-8f);
    #pragma unroll
    for (int i = 0; i < 16; i++) {
        float c = (22.f / 15.f) * (float)i;
        float z = (dcb - c) * (1.f / 1.375f);
        fe[i] = __expf(-z * z);
    }
    #pragma unroll
    for (int a = 0; a < 5; a++) {
        float vx = pj[a * 3 + 0] - can0;
        float vy = pj[a * 3 + 1] - can1;
        float vz = pj[a * 3 + 2] - can2;
        float invv = rsqrtf(vx * vx + vy * vy + vz * vz + 1e-8f);
        fe[16 + a * 3 + 0] = vx * invv;
        fe[16 + a * 3 + 1] = vy * invv;
        fe[16 + a * 3 + 2] = vz * invv;
    }
    #pragma unroll
    for (int b = 0; b < 3; b++)
        #pragma unroll
        for (int c2 = 0; c2 < 3; c2++)
            fe[31 + b * 3 + c2] = Rn[0 + b] * Rj[0 + c2] + Rn[3 + b] * Rj[3 + c2] + Rn[6 + b] * Rj[6 + c2];
    float t0 = pj[3] - can0, t1 = pj[4] - can1, t2 = pj[5] - can2;
    #pragma unroll
    for (int b = 0; b < 3; b++)
        fe[40 + b] = Rn[0 + b] * t0 + Rn[3 + b] * t1 + Rn[6 + b] * t2;

    #pragma unroll
    for (int q = 0; q < 8; q++) {
        uint4 w;
        float v0 = (q * 8 + 0 < 43) ? fe[q * 8 + 0] : 0.f;
        float v1 = (q * 8 + 1 < 43) ? fe[q * 8 + 1] : 0.f;
        float v2 = (q * 8 + 2 < 43) ? fe[q * 8 + 2] : 0.f;
        float v3 = (q * 8 + 3 < 43) ? fe[q * 8 + 3] : 0.f;
        float v4 = (q * 8 + 4 < 43) ? fe[q * 8 + 4] : 0.f;
        float v5 = (q * 8 + 5 < 43) ? fe[q * 8 + 5] : 0.f;
        float v6 = (q * 8 + 6 < 43) ? fe[q * 8 + 6] : 0.f;
        float v7 = (q * 8 + 7 < 43) ? fe[q * 8 + 7] : 0.f;
        w.x = pk2(v0, v1); w.y = pk2(v2, v3); w.z = pk2(v4, v5); w.w = pk2(v6, v7);
        *(uint4*)&feat[(size_t)p * 64 + q * 8] = w;
    }
    float rt0 = fe[40], rt1 = fe[41], rt2 = fe[42];
    float dr2 = rt0 * rt0 + rt1 * rt1 + rt2 * rt2 + 1e-8f;
    float invdr = rsqrtf(dr2);
    float drel = dr2 * invdr;
    ushort* tf = tfb + (size_t)n * 608 + k * 19;
    #pragma unroll
    for (int i = 0; i < 16; i++) {
        float c = (22.f / 15.f) * (float)i;
        float z = (drel - c) * (1.f / 1.375f);
        tf[i] = f2bf(__expf(-z * z));
    }
    tf[16] = f2bf(rt0 * invdr);
    tf[17] = f2bf(rt1 * invdr);
    tf[18] = f2bf(rt2 * invdr);
}

// ---------------- pair stage0: feat-proj MFMA + relpos + LN, in-place ----------------
__global__ __launch_bounds__(256) void pair_pre_kernel(
    ushort* feat, const int* __restrict__ relidx,
    const float* __restrict__ w_relpos, const ushort* __restrict__ pf,
    const float* __restrict__ lng, const float* __restrict__ lnb) {
    int tid = threadIdx.x;
    int wid = tid >> 6, lane = tid & 63, hi = lane >> 4, lo = lane & 15;
    bf16x8 wf[8];
    #pragma unroll
    for (int fs = 0; fs < 8; fs++) wf[fs] = *(const bf16x8*)&pf[10240 + fs * 512 + lane * 8];
    float sg_r[4][4], sbt_r[4][4];
    #pragma unroll
    for (int f = 0; f < 4; f++)
        #pragma unroll
        for (int r = 0; r < 4; r++) {
            int c = 16 * f + 4 * hi + r;
            sg_r[f][r] = lng[c];
            sbt_r[f][r] = lnb[c];
        }
    const f32x4 zz = {0.f, 0.f, 0.f, 0.f};
    for (int t = blockIdx.x * 4 + wid; t < (NN * KK / 16); t += 16384) {
        int r0 = t << 4;
        bf16x8 bp0 = *(const bf16x8*)(feat + (size_t)(r0 + lo) * 64 + hi * 8);
        bf16x8 bp1 = *(const bf16x8*)(feat + (size_t)(r0 + lo) * 64 + 32 + hi * 8);
        f32x4 a0f[4];
        #pragma unroll
        for (int f = 0; f < 4; f++) {
            a0f[f] = __builtin_amdgcn_mfma_f32_16x16x32_bf16(wf[f * 2 + 0], bp0, zz, 0, 0, 0);
            a0f[f] = __builtin_amdgcn_mfma_f32_16x16x32_bf16(wf[f * 2 + 1], bp1, a0f[f], 0, 0, 0);
        }
        int ridx = relidx[r0 + lo];
        float val[4][4];
        float part = 0.f;
        #pragma unroll
        for (int f = 0; f < 4; f++)
            #pragma unroll
            for (int r = 0; r < 4; r++) {
                int c = 16 * f + 4 * hi + r;
                float rv = (ridx >= 0) ? w_relpos[ridx * 64 + c] : 0.f;
                float v = a0f[f][r] + rv;
                val[f][r] = v;
                part += v;
            }
        part += __shfl_xor(part, 16);
        part += __shfl_xor(part, 32);
        float mean = part * (1.f / 64.f);
        float v2 = 0.f;
        #pragma unroll
        for (int f = 0; f < 4; f++)
            #pragma unroll
            for (int r = 0; r < 4; r++) {
                float dv = val[f][r] - mean;
                val[f][r] = dv;
                v2 += dv * dv;
            }
        v2 += __shfl_xor(v2, 16);
        v2 += __shfl_xor(v2, 32);
        float rs = rsqrtf(v2 * (1.f / 64.f) + 1e-5f);
        #pragma unroll
        for (int f = 0; f < 4; f++) {
            float v0 = val[f][0] * rs * sg_r[f][0] + sbt_r[f][0];
            float v1 = val[f][1] * rs * sg_r[f][1] + sbt_r[f][1];
            float v2b = val[f][2] * rs * sg_r[f][2] + sbt_r[f][2];
            float v3 = val[f][3] * rs * sg_r[f][3] + sbt_r[f][3];
            *(uint2*)(feat + (size_t)(r0 + lo) * 64 + 16 * f + 4 * hi) =
                make_uint2(pk2(v0, v1), pk2(v2b, v3));
        }
    }
}

// ---------------- pair MLP: pln -> 128 gelu -> @W2B -> bias (bf16) ----------------
__global__ __launch_bounds__(256) void pair_mlp2_kernel(
    const ushort* __restrict__ pln, const ushort* __restrict__ pf,
    const float* __restrict__ b_p1, const float* __restrict__ b2b,
    ushort* __restrict__ bias) {
    __shared__ __align__(16) ushort hx[4 * 2048];
    int tid = threadIdx.x;
    int wid = tid >> 6, lane = tid & 63, hi = lane >> 4, lo = lane & 15;
    bf16x8 w1f[16];
    #pragma unroll
    for (int fs = 0; fs < 16; fs++) w1f[fs] = *(const bf16x8*)&pf[fs * 512 + lane * 8];
    bf16x8 w2f[4];
    #pragma unroll
    for (int s2 = 0; s2 < 4; s2++) w2f[s2] = *(const bf16x8*)&pf[8192 + s2 * 512 + lane * 8];
    float b2b_r[4];
    #pragma unroll
    for (int r = 0; r < 4; r++) b2b_r[r] = (hi < 2) ? b2b[4 * hi + r] : 0.f;
    float sb1_r[8][4];
    #pragma unroll
    for (int f = 0; f < 8; f++)
        #pragma unroll
        for (int r = 0; r < 4; r++) sb1_r[f][r] = b_p1[16 * f + 4 * hi + r];

    ushort* hxw = &hx[wid * 2048];
    const f32x4 zz = {0.f, 0.f, 0.f, 0.f};
    for (int t = blockIdx.x * 4 + wid; t < (NN * KK / 16); t += 16384) {
        int r0 = t << 4;
        bf16x8 bh0 = *(const bf16x8*)(pln + (size_t)(r0 + lo) * 64 + hi * 8);
        bf16x8 bh1 = *(const bf16x8*)(pln + (size_t)(r0 + lo) * 64 + 32 + hi * 8);
        #pragma unroll
        for (int f = 0; f < 8; f++) {
            f32x4 acch = __builtin_amdgcn_mfma_f32_16x16x32_bf16(w1f[f * 2 + 0], bh0, zz, 0, 0, 0);
            acch = __builtin_amdgcn_mfma_f32_16x16x32_bf16(w1f[f * 2 + 1], bh1, acch, 0, 0, 0);
            int c0 = 16 * f + 4 * hi;
            float v0 = gelu_f(acch[0] + sb1_r[f][0]);
            float v1 = gelu_f(acch[1] + sb1_r[f][1]);
            float v2b = gelu_f(acch[2] + sb1_r[f][2]);
            float v3 = gelu_f(acch[3] + sb1_r[f][3]);
            int idx = (lo * 128 + c0) ^ ((lo & 7) << 3);
            *(uint2*)&hxw[idx] = make_uint2(pk2(v0, v1), pk2(v2b, v3));
        }
        f32x4 acc = zz;
        #pragma unroll
        for (int s2 = 0; s2 < 4; s2++) {
            int idx = (lo * 128 + 32 * s2 + 8 * hi) ^ ((lo & 7) << 3);
            bf16x8 bh = *(const bf16x8*)&hxw[idx];
            acc = __builtin_amdgcn_mfma_f32_16x16x32_bf16(w2f[s2], bh, acc, 0, 0, 0);
        }
        if (hi < 2) {
            int n = r0 >> 5, kb = (r0 & 31) + lo;
            #pragma unroll
            for (int r = 0; r < 4; r++)
                bias[(size_t)n * 256 + (4 * hi + r) * 32 + kb] = f2bf(acc[r] + b2b_r[r]);
        }
    }
}

// ---------------- GEMM core T (BM=128, BN=128) ----------------
__device__ __forceinline__ void gemm_coreT(
    const ushort* __restrict__ A, const ushort* __restrict__ Wt,
    int K, int row0, int colW0, int tid,
    ushort* sA, ushort* sB, f32x4 acc[4][4]) {
    int wid = tid >> 6, lane = tid & 63, lo = lane & 15, hi = lane >> 4;
    int wr = wid >> 1, wc = wid & 1;
    int ar = tid >> 1, akh = (tid & 1) * 16;
    for (int kt = 0; kt < K; kt += 32) {
        const ushort* ap = &A[(size_t)(row0 + ar) * K + kt + akh];
        uint4 a01 = *(const uint4*)ap;
        uint4 a23 = *(const uint4*)(ap + 8);
        const ushort* bp = &Wt[(size_t)(colW0 + ar) * K + kt + akh];
        uint4 b01 = *(const uint4*)bp;
        uint4 b23 = *(const uint4*)(bp + 8);
        __syncthreads();
        *(uint4*)&sA[ar * 40 + akh] = a01;
        *(uint4*)&sA[ar * 40 + akh + 8] = a23;
        *(uint4*)&sB[ar * 40 + akh] = b01;
        *(uint4*)&sB[ar * 40 + akh + 8] = b23;
        __syncthreads();
        bf16x8 af[4], bfr[4];
        #pragma unroll
        for (int mi = 0; mi < 4; mi++) af[mi] = *(const bf16x8*)&sA[(wr * 64 + mi * 16 + lo) * 40 + hi * 8];
        #pragma unroll
        for (int ni = 0; ni < 4; ni++) bfr[ni] = *(const bf16x8*)&sB[(wc * 64 + ni * 16 + lo) * 40 + hi * 8];
        #pragma unroll
        for (int mi = 0; mi < 4; mi++)
            #pragma unroll
            for (int ni = 0; ni < 4; ni++)
                acc[mi][ni] = __builtin_amdgcn_mfma_f32_16x16x32_bf16(af[mi], bfr[ni], acc[mi][ni], 0, 0, 0);
    }
}

// ---------------- t1 GEMM ----------------
__global__ __launch_bounds__(256) void gemm_t1T(
    const ushort* __restrict__ A, const ushort* __restrict__ Wt, ushort* __restrict__ C,
    int K, int Nc) {
    __shared__ __align__(16) ushort sA[128 * 40];
    __shared__ __align__(16) ushort sB[128 * 40];
    int row0 = blockIdx.y * 128, col0 = blockIdx.x * 128;
    int tid = threadIdx.x;
    const f32x4 zz = {0.f, 0.f, 0.f, 0.f};
    f32x4 acc[4][4] = {{zz, zz, zz, zz}, {zz, zz, zz, zz}, {zz, zz, zz, zz}, {zz, zz, zz, zz}};
    gemm_coreT(A, Wt, K, row0, col0, tid, sA, sB, acc);
    int wid = tid >> 6, lane = tid & 63, lo = lane & 15, hi = lane >> 4;
    int wr = wid >> 1, wc = wid & 1;
    #pragma unroll
    for (int ni = 0; ni < 4; ni++) {
        int col = col0 + wc * 64 + ni * 16 + lo;
        #pragma unroll
        for (int mi = 0; mi < 4; mi++) {
            #pragma unroll
            for (int r = 0; r < 4; r++) {
                int row = row0 + wr * 64 + mi * 16 + hi * 4 + r;
                C[(size_t)row * Nc + col] = f2bf(gelu_f(acc[mi][ni][r]));
            }
        }
    }
}

// ---------------- small-tile GEMM (BM=64, BN=64) ----------------
__global__ __launch_bounds__(256) void gemm_n64s(
    const ushort* __restrict__ A, const ushort* __restrict__ Wt, float* __restrict__ C,
    int K, int Nc, const float* __restrict__ bias, const float* __restrict__ addp) {
    __shared__ __align__(16) ushort sA[64 * 40];
    __shared__ __align__(16) ushort sB[64 * 40];
    int row0 = blockIdx.y * 64, col0 = blockIdx.x * 64;
    int tid = threadIdx.x;
    int wid = tid >> 6, lane = tid & 63, lo = lane & 15, hi = lane >> 4;
    int wr = wid >> 1, wc = wid & 1;
    int ar = tid >> 2, akh = (tid & 3) * 8;
    const f32x4 zz = {0.f, 0.f, 0.f, 0.f};
    f32x4 acc[2][2] = {{zz, zz}, {zz, zz}};
    for (int kt = 0; kt < K; kt += 32) {
        uint4 a0 = *(const uint4*)&A[(size_t)(row0 + ar) * K + kt + akh];
        uint4 b0 = *(const uint4*)&Wt[(size_t)(col0 + ar) * K + kt + akh];
        __syncthreads();
        *(uint4*)&sA[ar * 40 + akh] = a0;
        *(uint4*)&sB[ar * 40 + akh] = b0;
        __syncthreads();
        bf16x8 af[2], bfr[2];
        #pragma unroll
        for (int mi = 0; mi < 2; mi++) af[mi] = *(const bf16x8*)&sA[(wr * 32 + mi * 16 + lo) * 40 + hi * 8];
        #pragma unroll
        for (int ni = 0; ni < 2; ni++) bfr[ni] = *(const bf16x8*)&sB[(wc * 32 + ni * 16 + lo) * 40 + hi * 8];
        #pragma unroll
        for (int mi = 0; mi < 2; mi++)
            #pragma unroll
            for (int ni = 0; ni < 2; ni++)
                acc[mi][ni] = __builtin_amdgcn_mfma_f32_16x16x32_bf16(af[mi], bfr[ni], acc[mi][ni], 0, 0, 0);
    }
    #pragma unroll
    for (int ni = 0; ni < 2; ni++) {
        int col = col0 + wc * 32 + ni * 16 + lo;
        float bc = bias ? bias[col] : 0.f;
        #pragma unroll
        for (int mi = 0; mi < 2; mi++) {
            #pragma unroll
            for (int r = 0; r < 4; r++) {
                int row = row0 + wr * 32 + mi * 16 + hi * 4 + r;
                float v = acc[mi][ni][r] + bc;
                if (addp) v += addp[(size_t)row * Nc + col];
                C[(size_t)row * Nc + col] = v;
            }
        }
    }
}

// ---------------- fused QKV GEMM T (all bf16 outputs) ----------------
__global__ __launch_bounds__(256) void gemm_qkvT(
    const ushort* __restrict__ A, const ushort* __restrict__ Wt3,
    ushort* __restrict__ qb, ushort* __restrict__ kb, ushort* __restrict__ vb) {
    __shared__ __align__(16) ushort sA[128 * 40];
    __shared__ __align__(16) ushort sB[128 * 40];
    int row0 = blockIdx.y * 128, col0 = blockIdx.x * 128;
    int wsel = col0 >> 8, colW = col0 & 255;
    int tid = threadIdx.x;
    const f32x4 zz = {0.f, 0.f, 0.f, 0.f};
    f32x4 acc[4][4] = {{zz, zz, zz, zz}, {zz, zz, zz, zz}, {zz, zz, zz, zz}, {zz, zz, zz, zz}};
    gemm_coreT(A, Wt3, 256, row0, col0, tid, sA, sB, acc);
    int wid = tid >> 6, lane = tid & 63, lo = lane & 15, hi = lane >> 4;
    int wr = wid >> 1, wc = wid & 1;
    ushort* O = (wsel == 0) ? qb : (wsel == 1) ? kb : vb;
    #pragma unroll
    for (int ni = 0; ni < 4; ni++) {
        int colo = colW + wc * 64 + ni * 16 + lo;
        #pragma unroll
        for (int mi = 0; mi < 4; mi++) {
            #pragma unroll
            for (int r = 0; r < 4; r++) {
                int row = row0 + wr * 64 + mi * 16 + hi * 4 + r;
                O[(size_t)row * 256 + colo] = f2bf(acc[mi][ni][r]);
            }
        }
    }
}

// ---------------- fused FFN GEMM T ----------------
__global__ __launch_bounds__(256) void gemm_ffnT(
    const ushort* __restrict__ A, const ushort* __restrict__ Wt4,
    ushort* __restrict__ o0, ushort* __restrict__ o1,
    ushort* __restrict__ o2, ushort* __restrict__ o3) {
    __shared__ __align__(16) ushort sA[128 * 40];
    __shared__ __align__(16) ushort sB[128 * 40];
    int row0 = blockIdx.y * 128, col0 = blockIdx.x * 128;
    int wsel = col0 >> 9, colW = col0 & 511;
    ushort* O = (wsel == 0) ? o0 : (wsel == 1) ? o1 : (wsel == 2) ? o2 : o3;
    int tid = threadIdx.x;
    const f32x4 zz = {0.f, 0.f, 0.f, 0.f};
    f32x4 acc[4][4] = {{zz, zz, zz, zz}, {zz, zz, zz, zz}, {zz, zz, zz, zz}, {zz, zz, zz, zz}};
    gemm_coreT(A, Wt4, 256, row0, col0, tid, sA, sB, acc);
    int wid = tid >> 6, lane = tid & 63, lo = lane & 15, hi = lane >> 4;
    int wr = wid >> 1, wc = wid & 1;
    #pragma unroll
    for (int ni = 0; ni < 4; ni++) {
        int colo = colW + wc * 64 + ni * 16 + lo;
        #pragma unroll
        for (int mi = 0; mi < 4; mi++) {
            #pragma unroll
            for (int r = 0; r < 4; r++) {
                int row = row0 + wr * 64 + mi * 16 + hi * 4 + r;
                float v = acc[mi][ni][r];
                if (wsel > 0) v = gelu_f(v);
                O[(size_t)row * 512 + colo] = f2bf(v);
            }
        }
    }
}

// ---------------- attention (q, bias bf16) ----------------
__global__ __launch_bounds__(256) void attn_kernel(
    const ushort* __restrict__ q, const ushort* __restrict__ kp, const ushort* __restrict__ vp,
    const ushort* __restrict__ bias, const int* __restrict__ nbr, ushort* __restrict__ o) {
    int n = blockIdx.x;
    __shared__ float qs[256];
    __shared__ int js[32];
    __shared__ float ls[256];
    __shared__ __align__(16) uint4 vs[32 * 33];
    int t = threadIdx.x;
    qs[t] = bf2f(q[(size_t)n * 256 + t]);
    if (t < 32) js[t] = nbr[n * 32 + t];
    __syncthreads();
    int vrow = t >> 3, vseg = t & 7;
    const uint4* vsrc = (const uint4*)(vp + (size_t)js[vrow] * 256);
    uint4 vr0 = vsrc[vseg * 4 + 0];
    uint4 vr1 = vsrc[vseg * 4 + 1];
    uint4 vr2 = vsrc[vseg * 4 + 2];
    uint4 vr3 = vsrc[vseg * 4 + 3];
    int h = t >> 5, k = t & 31;
    int j = js[k];
    const bf16x8* kr = (const bf16x8*)(kp + (size_t)j * 256 + h * 32);
    bf16x8 kv0 = kr[0], kv1 = kr[1], kv2 = kr[2], kv3 = kr[3];
    const float* qh = qs + h * 32;
    float dot = 0.f;
    #pragma unroll
    for (int i = 0; i < 8; i++) dot += qh[i] * bf2f((ushort)kv0[i]);
    #pragma unroll
    for (int i = 0; i < 8; i++) dot += qh[8 + i] * bf2f((ushort)kv1[i]);
    #pragma unroll
    for (int i = 0; i < 8; i++) dot += qh[16 + i] * bf2f((ushort)kv2[i]);
    #pragma unroll
    for (int i = 0; i < 8; i++) dot += qh[24 + i] * bf2f((ushort)kv3[i]);
    float l = dot * 0.17677669529663687f + bf2f(bias[(size_t)n * 256 + t]);
    float mx = l;
    #pragma unroll
    for (int m = 16; m > 0; m >>= 1) mx = fmaxf(mx, __shfl_xor(mx, m));
    float e = __expf(l - mx);
    float sum = e;
    #pragma unroll
    for (int m = 16; m > 0; m >>= 1) sum += __shfl_xor(sum, m);
    ls[t] = e / sum;
    vs[vrow * 33 + vseg * 4 + 0] = vr0;
    vs[vrow * 33 + vseg * 4 + 1] = vr1;
    vs[vrow * 33 + vseg * 4 + 2] = vr2;
    vs[vrow * 33 + vseg * 4 + 3] = vr3;
    __syncthreads();
    const ushort* vsu = (const ushort*)vs;
    const float* lh = ls + h * 32;
    float acc = 0.f;
    #pragma unroll
    for (int kk = 0; kk < 32; kk++)
        acc += lh[kk] * bf2f(vsu[kk * 264 + h * 32 + k]);
    o[(size_t)n * 256 + t] = f2bf(acc);
}

// ---------------- LN(a+b) ----------------
__global__ __launch_bounds__(256) void ln_add_kernel(
    const float* __restrict__ a, const float* __restrict__ b,
    const float* __restrict__ g, const float* __restrict__ be,
    float* __restrict__ xout, ushort* __restrict__ xbout, float* __restrict__ sout) {
    int row = blockIdx.x * 4 + (threadIdx.x >> 6);
    int lane = threadIdx.x & 63;
    size_t base = (size_t)row * 256 + lane * 4;
    float4 av = *(const float4*)(a + base);
    float4 bv = *(const float4*)(b + base);
    float s0 = av.x + bv.x, s1 = av.y + bv.y, s2 = av.z + bv.z, s3 = av.w + bv.w;
    float sum = wave_sum64(s0 + s1 + s2 + s3);
    float mean = sum * (1.f / 256.f);
    float d0 = s0 - mean, d1 = s1 - mean, d2 = s2 - mean, d3 = s3 - mean;
    float v = wave_sum64(d0 * d0 + d1 * d1 + d2 * d2 + d3 * d3);
    float rs = rsqrtf(v * (1.f / 256.f) + 1e-5f);
    float4 gv = *(const float4*)(g + lane * 4);
    float4 bev = *(const float4*)(be + lane * 4);
    float4 xo;
    xo.x = d0 * rs * gv.x + bev.x;
    xo.y = d1 * rs * gv.y + bev.y;
    xo.z = d2 * rs * gv.z + bev.z;
    xo.w = d3 * rs * gv.w + bev.w;
    *(float4*)(xout + base) = xo;
    *(uint2*)(xbout + base) = make_uint2(pk2(xo.x, xo.y), pk2(xo.z, xo.w));
    float4 so; so.x = s0; so.y = s1; so.z = s2; so.w = s3;
    *(float4*)(sout + base) = so;
}

// ---------------- segment partial sums ----------------
__global__ __launch_bounds__(256) void seg_partial_kernel(
    const ushort* __restrict__ up, const int* __restrict__ batch, const int* __restrict__ chain,
    float* __restrict__ mb_acc, float* __restrict__ mc_acc) {
    int r0 = blockIdx.x * 32;
    int t = threadIdx.x;
    float ab0 = 0.f, ab1 = 0.f, ac0 = 0.f, ac1 = 0.f;
    int curb = batch[r0], curc = chain[r0];
    for (int r = r0; r < r0 + 32; r++) {
        int b = batch[r], c = chain[r];
        if (b != curb) {
            atomicAdd(&mb_acc[curb * 512 + t], ab0);
            atomicAdd(&mb_acc[curb * 512 + 256 + t], ab1);
            ab0 = ab1 = 0.f; curb = b;
        }
        if (c != curc) {
            atomicAdd(&mc_acc[curc * 512 + t], ac0);
            atomicAdd(&mc_acc[curc * 512 + 256 + t], ac1);
            ac0 = ac1 = 0.f; curc = c;
        }
        float v0 = bf2f(up[(size_t)r * 512 + t]);
        float v1 = bf2f(up[(size_t)r * 512 + 256 + t]);
        ab0 += v0; ab1 += v1; ac0 += v0; ac1 += v1;
    }
    atomicAdd(&mb_acc[curb * 512 + t], ab0);
    atomicAdd(&mb_acc[curb * 512 + 256 + t], ab1);
    atomicAdd(&mc_acc[curc * 512 + t], ac0);
    atomicAdd(&mc_acc[curc * 512 + 256 + t], ac1);
}

// ---------------- hidden combine (raw sums * rcnt) ----------------
__global__ __launch_bounds__(256) void hidden_kernel(
    const ushort* __restrict__ up, const ushort* __restrict__ cg, const ushort* __restrict__ bg,
    ushort* __restrict__ lg, const float* __restrict__ mb, const float* __restrict__ mc,
    const int* __restrict__ batch, const int* __restrict__ chain,
    const float* __restrict__ rcnt) {
    size_t e4 = ((size_t)blockIdx.x * 256 + threadIdx.x) * 4;
    int n = (int)(e4 >> 9), d = (int)(e4 & 511);
    float rb = rcnt[batch[n]];
    float rc = rcnt[32 + chain[n]];
    float4 mbv = *(const float4*)&mb[batch[n] * 512 + d];
    float4 mcv = *(const float4*)&mc[chain[n] * 512 + d];
    uint2 u_up = *(const uint2*)&up[e4];
    uint2 u_cg = *(const uint2*)&cg[e4];
    uint2 u_bg = *(const uint2*)&bg[e4];
    uint2 u_lg = *(const uint2*)&lg[e4];
    float h0 = bf2f((ushort)u_bg.x) * (mbv.x * rb) + bf2f((ushort)u_cg.x) * (mcv.x * rc)
             + bf2f((ushort)u_lg.x) * bf2f((ushort)u_up.x);
    float h1 = bf2f((ushort)(u_bg.x >> 16)) * (mbv.y * rb) + bf2f((ushort)(u_cg.x >> 16)) * (mcv.y * rc)
             + bf2f((ushort)(u_lg.x >> 16)) * bf2f((ushort)(u_up.x >> 16));
    float h2 = bf2f((ushort)u_bg.y) * (mbv.z * rb) + bf2f((ushort)u_cg.y) * (mcv.z * rc)
             + bf2f((ushort)u_lg.y) * bf2f((ushort)u_up.y);
    float h3 = bf2f((ushort)(u_bg.y >> 16)) * (mbv.w * rb) + bf2f((ushort)(u_cg.y >> 16)) * (mcv.w * rc)
             + bf2f((ushort)(u_lg.y >> 16)) * bf2f((ushort)(u_up.y >> 16));
    *(uint2*)&lg[e4] = make_uint2(pk2(h0, h1), pk2(h2, h3));
}

// ---------------- final ----------------
__global__ __launch_bounds__(256) void final_kernel(
    const float* __restrict__ x1, const float* __restrict__ y2, const float* __restrict__ inc1,
    const float* __restrict__ ug, const float* __restrict__ ub,
    const float* __restrict__ fg, const float* __restrict__ fb, float* __restrict__ out) {
    int row = blockIdx.x * 4 + (threadIdx.x >> 6);
    int lane = threadIdx.x & 63;
    size_t base = (size_t)row * 256 + lane * 4;
    float4 xv = *(const float4*)(x1 + base);
    float4 yv = *(const float4*)(y2 + base);
    float4 iv = *(const float4*)(inc1 + base);
    float s0 = xv.x + yv.x, s1 = xv.y + yv.y, s2 = xv.z + yv.z, s3 = xv.w + yv.w;
    float t0 = iv.x + yv.x, t1 = iv.y + yv.y, t2 = iv.z + yv.z, t3 = iv.w + yv.w;
    float sums = wave_sum64(s0 + s1 + s2 + s3);
    float means = sums * (1.f / 256.f);
    float sd0 = s0 - means, sd1 = s1 - means, sd2 = s2 - means, sd3 = s3 - means;
    float vs = wave_sum64(sd0 * sd0 + sd1 * sd1 + sd2 * sd2 + sd3 * sd3);
    float rss = rsqrtf(vs * (1.f / 256.f) + 1e-5f);
    float sumt = wave_sum64(t0 + t1 + t2 + t3);
    float meant = sumt * (1.f / 256.f);
    float td0 = t0 - meant, td1 = t1 - meant, td2 = t2 - meant, td3 = t3 - meant;
    float vt = wave_sum64(td0 * td0 + td1 * td1 + td2 * td2 + td3 * td3);
    float rst = rsqrtf(vt * (1.f / 256.f) + 1e-5f);
    float4 ugv = *(const float4*)(ug + lane * 4);
    float4 ubv = *(const float4*)(ub + lane * 4);
    float4 fgv = *(const float4*)(fg + lane * 4);
    float4 fbv = *(const float4*)(fb + lane * 4);
    float4 ov;
    ov.x = (sd0 * rss * ugv.x + ubv.x) + (td0 * rst * fgv.x + fbv.x);
    ov.y = (sd1 * rss * ugv.y + ubv.y) + (td1 * rst * fgv.y + fbv.y);
    ov.z = (sd2 * rss * ugv.z + ubv.z) + (td2 * rst * fgv.z + fbv.z);
    ov.w = (sd3 * rss * ugv.w + ubv.w) + (td3 * rst * fgv.w + fbv.w);
    *(float4*)(out + base) = ov;
}

// ---------------- launch ----------------
extern "C" void kernel_launch(void* const* d_in, const int* in_sizes, int n_in,
                              void* d_out, int out_size, void* d_ws, size_t ws_size,
                              hipStream_t stream) {
    const float* local    = (const float*)d_in[0];
    const float* pos      = (const float*)d_in[1];
    const int*   nbr      = (const int*)d_in[2];
    const int*   resi     = (const int*)d_in[3];
    const int*   chain    = (const int*)d_in[4];
    const int*   batch    = (const int*)d_in[5];
    const float* w_relpos = (const float*)d_in[7];
    const float* w_dist   = (const float*)d_in[8];
    const float* w_dir    = (const float*)d_in[9];
    const float* w_rot    = (const float*)d_in[10];
    const float* ln_pair_g = (const float*)d_in[11];
    const float* ln_pair_b = (const float*)d_in[12];
    const float* w_p1     = (const float*)d_in[13];
    const float* b_p1     = (const float*)d_in[14];
    const float* w_p2     = (const float*)d_in[15];
    const float* b_p2     = (const float*)d_in[16];
    const float* wq       = (const float*)d_in[17];
    const float* wk       = (const float*)d_in[18];
    const float* wv       = (const float*)d_in[19];
    const float* wb       = (const float*)d_in[20];
    const float* wo       = (const float*)d_in[21];
    const float* ln_a_g   = (const float*)d_in[22];
    const float* ln_a_b   = (const float*)d_in[23];
    const float* w_t1     = (const float*)d_in[24];
    const float* w_t2     = (const float*)d_in[25];
    const float* w_up     = (const float*)d_in[26];
    const float* w_lg     = (const float*)d_in[27];
    const float* w_cg     = (const float*)d_in[28];
    const float* w_bg     = (const float*)d_in[29];
    const float* w_out    = (const float*)d_in[30];
    const float* b_out    = (const float*)d_in[31];
    const float* ln_u_g   = (const float*)d_in[32];
    const float* ln_u_b   = (const float*)d_in[33];
    const float* ln_f_g   = (const float*)d_in[34];
    const float* ln_f_b   = (const float*)d_in[35];

    float* ws = (float*)d_ws;
    ushort* biasu    = (ushort*)(ws + 73728);    // N*256 bf16
    float* tfeat_out = ws + 2170880;       // -> 4268032
    float* x1        = ws + 4268032;       // -> 6365184
    float* inc1      = ws + 6365184;       // -> 8462336
    ushort* featb    = (ushort*)(ws + 8462336);  // -> 16850944
    int* relidx      = (int*)(ws + 16850944);    // -> 17113088
    ushort* tfb      = (ushort*)(ws + 17113088); // -> 19603456
    ushort* wt       = (ushort*)(ws + 19603456); // -> 20283392
    ushort* x1b      = (ushort*)(ws + 20283392); // -> 21331968
    ushort* localb   = (ushort*)(ws + 21331968); // -> 22380544
    ushort* tmp512u  = (ushort*)(ws + 22380544); // -> 24477696
    float* y2        = ws + 22380544;      // over tmp512u after t2 consumed
    float* yb        = ws + 17113088;      // over tfb after t1 consumed
    ushort* qbu      = (ushort*)(ws + 8462336);  // phase 2 over featb (consumed)
    ushort* kbu      = (ushort*)(ws + 10559488);
    ushort* vbu      = (ushort*)(ws + 11608064);
    ushort* obu      = (ushort*)(ws + 12656640);
    ushort* upbu     = (ushort*)(ws + 8462336);  // phase 3
    ushort* lgbu     = (ushort*)(ws + 10559488);
    ushort* cgbu     = (ushort*)(ws + 12656640);
    ushort* bgbu     = (ushort*)(ws + 14753792);
    float* mb        = ws + 24477696;
    float* mc        = ws + 24494080;
    ushort* pfmt     = (ushort*)(ws + 24526848);
    float* b2b       = ws + 24535040;
    float* rcnt      = ws + 24535048;      // 96 floats

    prep_kernel<<<3453, 256, 0, stream>>>(local, w_p1, w_p2, b_p2, wb,
                                          w_dist, w_dir, w_rot, batch, chain,
                                          w_up, w_lg, w_cg, w_bg, wq, wk, wv,
                                          w_t1, w_t2, wo, w_out,
                                          localb, pfmt, wt, b2b, rcnt, mb);
    pair_raw_kernel<<<NN * KK / 256, 256, 0, stream>>>(pos, nbr, resi, chain,
                                                       featb, relidx, tfb);
    pair_pre_kernel<<<4096, 256, 0, stream>>>(featb, relidx, w_relpos, pfmt,
                                              ln_pair_g, ln_pair_b);
    pair_mlp2_kernel<<<4096, 256, 0, stream>>>(featb, pfmt, b_p1, b2b, biasu);
    // tfeat MLP
    gemm_t1T<<<dim3(4, 64), 256, 0, stream>>>(tfb, wt + 720896, tmp512u, 608, 512);
    gemm_n64s<<<dim3(4, 128), 256, 0, stream>>>(tmp512u, wt + 1032192, tfeat_out, 512, 256,
                                                nullptr, nullptr);
    // qkv
    gemm_qkvT<<<dim3(6, 64), 256, 0, stream>>>(localb, wt + 524288, qbu, kbu, vbu);
    attn_kernel<<<NN, 256, 0, stream>>>(qbu, kbu, vbu, biasu, nbr, obu);
    gemm_n64s<<<dim3(4, 128), 256, 0, stream>>>(obu, wt + 1163264, yb, 256, 256,
                                                nullptr, nullptr);
    ln_add_kernel<<<NN / 4, 256, 0, stream>>>(local, yb, ln_a_g, ln_a_b, x1, x1b, inc1);
    // FFN
    gemm_ffnT<<<dim3(16, 64), 256, 0, stream>>>(x1b, wt, upbu, lgbu, cgbu, bgbu);
    seg_partial_kernel<<<NN / 32, 256, 0, stream>>>(upbu, batch, chain, mb, mc);
    hidden_kernel<<<NN * 512 / 1024, 256, 0, stream>>>(upbu, cgbu, bgbu, lgbu, mb, mc,
                                                       batch, chain, rcnt);
    gemm_n64s<<<dim3(4, 128), 256, 0, stream>>>(lgbu, wt + 1228800, y2, 512, 256,
                                                b_out, tfeat_out);
    final_kernel<<<NN / 4, 256, 0, stream>>>(x1, y2, inc1, ln_u_g, ln_u_b, ln_f_g, ln_f_b, (float*)d_out);
}